// Round 11
// baseline (366.604 us; speedup 1.0000x reference)
//
#include <hip/hip_runtime.h>

typedef __bf16 bf16x8 __attribute__((ext_vector_type(8)));
typedef __bf16 bf16x4 __attribute__((ext_vector_type(4)));
typedef __bf16 bf16x2 __attribute__((ext_vector_type(2)));
typedef float f32x4 __attribute__((ext_vector_type(4)));
typedef unsigned int u32;

// Problem constants: B (runtime), S=2048, D=1024, H=16, hd=64
#define QSCALE 0.18033688011112042f  // hd^-0.5 * log2(e), folded into Q

__device__ __forceinline__ void gld_lds16(const void* gsrc, void* ldst) {
  __builtin_amdgcn_global_load_lds(
      (const __attribute__((address_space(1))) u32*)gsrc,
      (__attribute__((address_space(3))) u32*)ldst, 16, 0, 0);
}

__device__ __forceinline__ float fexp2(float x) {
#if __has_builtin(__builtin_amdgcn_exp2f)
  return __builtin_amdgcn_exp2f(x);
#else
  return exp2f(x);
#endif
}

__device__ __forceinline__ u32 pkbf(float a, float b) {
  bf16x2 t; t[0] = (__bf16)a; t[1] = (__bf16)b;
  return __builtin_bit_cast(u32, t);
}

// ---------------- fp32 -> bf16 elementwise convert ----------------
__global__ __launch_bounds__(256) void cvt_f32_bf16(const float* __restrict__ src,
                                                    __bf16* __restrict__ dst, int n) {
  int i = (blockIdx.x * 256 + threadIdx.x) * 8;
  if (i >= n) return;
  const float4* p = (const float4*)(src + i);
  float4 a = p[0], b = p[1];
  bf16x8 v;
  v[0] = (__bf16)a.x; v[1] = (__bf16)a.y; v[2] = (__bf16)a.z; v[3] = (__bf16)a.w;
  v[4] = (__bf16)b.x; v[5] = (__bf16)b.y; v[6] = (__bf16)b.z; v[7] = (__bf16)b.w;
  *(bf16x8*)(dst + i) = v;
}

// ---------------- transpose fp32[R][C] -> bf16[C][R] ----------------
__global__ __launch_bounds__(256) void transpose_bf16(const float* __restrict__ src,
                                                      __bf16* __restrict__ dst, int R, int C) {
  __shared__ float tile[64 * 65];
  int c0 = blockIdx.x * 64, r0 = blockIdx.y * 64;
  int t = threadIdx.x;
  for (int i = 0; i < 16; ++i) {
    int idx = t + i * 256; int rr = idx >> 6, cc = idx & 63;
    tile[rr * 65 + cc] = src[(size_t)(r0 + rr) * C + (c0 + cc)];
  }
  __syncthreads();
  for (int i = 0; i < 16; ++i) {
    int idx = t + i * 256; int cc = idx >> 6, rr = idx & 63;
    dst[(size_t)(c0 + cc) * R + (r0 + rr)] = (__bf16)tile[rr * 65 + cc];
  }
}

// ---------------- 128x128-tile bf16 MFMA GEMM, A[M][K] @ Bt[N][K]^T ----------------
template<int EPI>
__global__ __launch_bounds__(256) void gemm128(
    const __bf16* __restrict__ A, const __bf16* __restrict__ Bt,
    int M, int N, int K,
    const float* __restrict__ bias0, const float* __restrict__ bias1,
    float* __restrict__ outf,
    __bf16* __restrict__ Qo, __bf16* __restrict__ Ko, __bf16* __restrict__ Vt)
{
  __shared__ __bf16 As[128 * 32];
  __shared__ __bf16 Bs[128 * 32];
  const int m0 = blockIdx.x * 128, n0 = blockIdx.y * 128;
  const int t = threadIdx.x, lane = t & 63, wave = t >> 6;
  const int wr = wave >> 1, wc = wave & 1;
  const int g = lane >> 4, ci = lane & 15;
  f32x4 acc[4][4];
#pragma unroll
  for (int i = 0; i < 4; ++i)
#pragma unroll
    for (int j = 0; j < 4; ++j) acc[i][j] = (f32x4){0.f, 0.f, 0.f, 0.f};

  const char* Ab = (const char*)A;
  const char* Bb = (const char*)Bt;
  for (int k0 = 0; k0 < K; k0 += 32) {
#pragma unroll
    for (int i = 0; i < 2; ++i) {
      int o = wave * 2048 + i * 1024 + lane * 16;
      int row = o >> 6, cb = o & 63;
      gld_lds16(Ab + ((size_t)(m0 + row) * K + k0) * 2 + cb, (char*)As + o);
      gld_lds16(Bb + ((size_t)(n0 + row) * K + k0) * 2 + cb, (char*)Bs + o);
    }
    __syncthreads();
    bf16x8 af[4], bfr[4];
#pragma unroll
    for (int i = 0; i < 4; ++i)
      af[i] = *(const bf16x8*)((const char*)As + (wr * 64 + i * 16 + ci) * 64 + g * 16);
#pragma unroll
    for (int j = 0; j < 4; ++j)
      bfr[j] = *(const bf16x8*)((const char*)Bs + (wc * 64 + j * 16 + ci) * 64 + g * 16);
#pragma unroll
    for (int i = 0; i < 4; ++i)
#pragma unroll
      for (int j = 0; j < 4; ++j)
        acc[i][j] = __builtin_amdgcn_mfma_f32_16x16x32_bf16(af[i], bfr[j], acc[i][j], 0, 0, 0);
    __syncthreads();
  }
#pragma unroll
  for (int j = 0; j < 4; ++j) {
    int c = n0 + wc * 64 + j * 16 + ci;
    float bias;
    if (EPI == 0) bias = (c < 1024) ? bias0[c] : bias1[c - 1024];
    else          bias = bias0[c];
#pragma unroll
    for (int i = 0; i < 4; ++i) {
      int rbase = m0 + wr * 64 + i * 16 + g * 4;
      if (EPI == 1) {
#pragma unroll
        for (int r = 0; r < 4; ++r)
          outf[(size_t)(rbase + r) * 1024 + c] = acc[i][j][r] + bias;
      } else {
        int b = rbase >> 11, n = rbase & 2047;
        if (c < 1024) {
          int h = c >> 6, d = c & 63;
#pragma unroll
          for (int r = 0; r < 4; ++r)
            Qo[(((size_t)(b * 16 + h)) * 2048 + n + r) * 64 + d] =
                (__bf16)((acc[i][j][r] + bias) * QSCALE);
        } else if (c < 2048) {
          int c2 = c - 1024; int h = c2 >> 6, d = c2 & 63;
#pragma unroll
          for (int r = 0; r < 4; ++r)
            Ko[(((size_t)(b * 16 + h)) * 2048 + n + r) * 64 + d] =
                (__bf16)(acc[i][j][r] + bias);
        } else {
          int c2 = c - 2048; int h = c2 >> 6, d = c2 & 63;
          bf16x4 pk;
#pragma unroll
          for (int r = 0; r < 4; ++r) pk[r] = (__bf16)(acc[i][j][r] + bias);
          *(bf16x4*)(Vt + ((size_t)(b * 16 + h) * 64 + d) * 2048 + n) = pk;
        }
      }
    }
  }
}

// ---------------- statspv: softmax stats + flash PV (O single-writer) ----------------
// [validated R9: K double-buffered, one barrier/round; stats row mapping via shuffles]
__global__ __launch_bounds__(1024) void statspv_kernel(
    const __bf16* __restrict__ Q, const __bf16* __restrict__ K, const __bf16* __restrict__ Vt,
    float* __restrict__ Smax, float* __restrict__ Sinv, __bf16* __restrict__ Ob)
{
  __shared__ __bf16 Kl[2][128 * 64]; // [m128][d64], chunk c stored at c^(m&7); dbuf
  __shared__ __bf16 Pp[16][16][40];  // per-wave P patch: [wave][n16][40] (80B rows)
  const int blk = blockIdx.x;
  const int b = blk >> 7, rem = blk & 127;
  const int h = rem >> 3, ns8 = rem & 7;
  const int w = threadIdx.x >> 6, lane = threadIdx.x & 63;
  const int g = lane >> 4, ci = lane & 15;
  const size_t bh = (size_t)(b * 16 + h);
  const __bf16* Qh = Q + bh * 2048 * 64;
  const __bf16* Kh = K + bh * 2048 * 64;
  const __bf16* Vh = Vt + bh * 64 * 2048;   // [d][s]
  const int n0 = ns8 * 256 + w * 16;

  bf16x8 qf0 = *(const bf16x8*)(Qh + (size_t)(n0 + ci) * 64 + g * 8);
  bf16x8 qf1 = *(const bf16x8*)(Qh + (size_t)(n0 + ci) * 64 + 32 + g * 8);

  const int so = threadIdx.x * 16;
  const int sm = so >> 7;
  const int sc = ((so >> 4) & 7) ^ (sm & 7);

  float rm = -3.0e30f, rs = 0.f;
  f32x4 oacc[4];
#pragma unroll
  for (int fd = 0; fd < 4; ++fd) oacc[fd] = (f32x4){0.f, 0.f, 0.f, 0.f};

  // prologue: stage tile 0
  gld_lds16(Kh + ((size_t)sm) * 64 + sc * 8, (char*)Kl[0] + so);
  __syncthreads();
  int cur = 0;

  for (int mt = 0; mt < 2048; mt += 128) {
    // issue next tile's stage FIRST (hides under this tile's compute)
    if (mt + 128 < 2048)
      gld_lds16(Kh + ((size_t)(mt + 128 + sm)) * 64 + sc * 8, (char*)Kl[cur ^ 1] + so);
    const char* Kc = (const char*)Kl[cur];
    f32x4 st[8];
#pragma unroll
    for (int fm = 0; fm < 8; ++fm) {
      int row = fm * 16 + ci;
      bf16x8 ka = *(const bf16x8*)(Kc + row * 128 + ((g ^ (ci & 7)) * 16));
      bf16x8 kb = *(const bf16x8*)(Kc + row * 128 + (((4 + g) ^ (ci & 7)) * 16));
      st[fm] = (f32x4){0.f, 0.f, 0.f, 0.f};
      st[fm] = __builtin_amdgcn_mfma_f32_16x16x32_bf16(ka, qf0, st[fm], 0, 0, 0);
      st[fm] = __builtin_amdgcn_mfma_f32_16x16x32_bf16(kb, qf1, st[fm], 0, 0, 0);
    }
    // per-round row max for col n=ci (cross-g combine so all 4 g-lanes agree)
    float tm = -3.0e30f;
#pragma unroll
    for (int fm = 0; fm < 8; ++fm)
#pragma unroll
      for (int r = 0; r < 4; ++r) tm = fmaxf(tm, st[fm][r]);
    tm = fmaxf(tm, __shfl_xor(tm, 16, 64));
    tm = fmaxf(tm, __shfl_xor(tm, 32, 64));
    float nm = fmaxf(rm, tm);
    float scale = fexp2(rm - nm);       // scale for row n = ci
    rs *= scale;
    // oacc rows are n = g*4+r -> fetch those rows' scales from lanes g*4+r
    f32x4 rsc;
#pragma unroll
    for (int r = 0; r < 4; ++r) rsc[r] = __shfl(scale, g * 4 + r, 64);
#pragma unroll
    for (int fd = 0; fd < 4; ++fd)
#pragma unroll
      for (int r = 0; r < 4; ++r) oacc[fd][r] *= rsc[r];
    rm = nm;
    // PV + sum, one 32-m slice at a time (P bf16 patch, validated layout)
    float ts = 0.f;
#pragma unroll
    for (int kk2 = 0; kk2 < 4; ++kk2) {
#pragma unroll
      for (int fm2 = 0; fm2 < 2; ++fm2) {
        f32x4 s = st[kk2 * 2 + fm2];
        f32x4 wv;
#pragma unroll
        for (int r = 0; r < 4; ++r) { wv[r] = fexp2(s[r] - nm); ts += wv[r]; }
        u32* pb = (u32*)((char*)&Pp[w][ci][0] + (fm2 * 8 + g * 2) * 4);
        pb[0] = pkbf(wv[0], wv[1]);
        pb[1] = pkbf(wv[2], wv[3]);
      }
      bf16x8 pa = *(const bf16x8*)((const char*)&Pp[w][ci][0] + g * 16);
#pragma unroll
      for (int fd = 0; fd < 4; ++fd) {
        bf16x8 vf = *(const bf16x8*)(Vh + (size_t)(fd * 16 + ci) * 2048 +
                                     mt + kk2 * 32 + g * 8);
        oacc[fd] = __builtin_amdgcn_mfma_f32_16x16x32_bf16(pa, vf, oacc[fd], 0, 0, 0);
      }
    }
    rs += ts;
    __syncthreads();
    cur ^= 1;
  }
  // combine per-lane partial sums across the 4 g-groups (rm already common)
#pragma unroll
  for (int off = 16; off <= 32; off <<= 1) {
    float om = __shfl_xor(rm, off, 64);
    float os = __shfl_xor(rs, off, 64);
    float nm = fmaxf(rm, om);
    rs = rs * fexp2(rm - nm) + os * fexp2(om - nm);
    rm = nm;
  }
  const float inv = 1.0f / rs;          // for row n = ci
  if (lane < 16) {
    size_t idx = bh * 2048 + n0 + ci;
    Smax[idx] = rm;
    Sinv[idx] = inv;
  }
  // O write rows are n = g*4+r -> fetch those rows' inv from lanes g*4+r
  f32x4 rinv;
#pragma unroll
  for (int r = 0; r < 4; ++r) rinv[r] = __shfl(inv, g * 4 + r, 64);
#pragma unroll
  for (int fd = 0; fd < 4; ++fd)
#pragma unroll
    for (int r = 0; r < 4; ++r) {
      int n = n0 + g * 4 + r;
      Ob[((size_t)(b * 2048 + n)) * 1024 + h * 64 + fd * 16 + ci] =
          (__bf16)(oacc[fd][r] * rinv[r]);
    }
}

// ---------------- weights-only kernel (v11: n-tile 64, register diet) ----------------
// Block = (b, n-tile 64, m-chunk 256); 16 waves = 16 heads; grid = B*256 -> 2 blocks/CU.
// Register diet vs R10's spilling attn_w8:
//   - rounds of 16 m (K frags = 8 VGPR, was 16); W2 buffers [16][272] (34.8KB total)
//   - softmax consts folded: C = smax + log2(sum); w = exp2(s - C)  (4 regs, was 8)
//   Persistent ~= qf 32 + C 4 + K 8 + addr ~4 = ~48; peak < 64 -> no spill at
//   __launch_bounds__(1024,8).
// Per round (16 m): load ka/kb once; 4 phases p=0..3:
//   compute nsub p -> W2[p&1]; bar; store W2[p&1] (1 nontemporal f32x4/thread,
//   overlaps next phase compute). Buffer reuse >= 1 barrier after its store's
//   ds_reads (drained by that barrier's lgkmcnt(0)) [R9/R10-validated pattern].
__global__ __launch_bounds__(1024, 8) void attn_w9(
    const __bf16* __restrict__ Q, const __bf16* __restrict__ K,
    const float* __restrict__ Smax, const float* __restrict__ Sinv,
    float* __restrict__ Wout)
{
  __shared__ float W2[2][16 * 272];   // 2 x 17.4 KB (phase ping-pong)
  // bijective XCD swizzle: each XCD gets a contiguous 64-block chunk
  // (same b, 2 mq values -> 1MB K slice, L2-resident across its 32 nt blocks)
  const int nwg = gridDim.x, cpx = nwg >> 3;
  const int o = blockIdx.x;
  const int blk = (o & 7) * cpx + (o >> 3);
  const int b = blk >> 8, r = blk & 255;
  const int mq = r >> 5, nt = r & 31;
  const int n0 = nt * 64, mstart = mq * 256;
  const int h = threadIdx.x >> 6;            // wave = head
  const int lane = threadIdx.x & 63;
  const int g = lane >> 4, ci = lane & 15;
  const size_t bh = (size_t)(b * 16 + h);
  const __bf16* Qh = Q + bh * 2048 * 64;
  const __bf16* Kh = K + bh * 2048 * 64;

  // folded softmax constant per n-subtile: C = smax + log2(sum)
  float C_[4];
  bf16x8 qf[4][2];
#pragma unroll
  for (int nsub = 0; nsub < 4; ++nsub) {
    size_t idx = bh * 2048 + n0 + nsub * 16 + ci;
    C_[nsub] = Smax[idx] - __log2f(Sinv[idx]);
    const __bf16* qp = Qh + (size_t)(n0 + nsub * 16 + ci) * 64;
    qf[nsub][0] = *(const bf16x8*)(qp + g * 8);
    qf[nsub][1] = *(const bf16x8*)(qp + 32 + g * 8);
  }

  // store-slot decode (constant per thread): slot = n*64 + m*4 + hq
  const int sn = threadIdx.x >> 6, sm2 = (threadIdx.x >> 2) & 15, shq = threadIdx.x & 3;
  const float* slds0 = &W2[0][sm2 * 272 + sn * 17 + shq * 4];
  const float* slds1 = &W2[1][sm2 * 272 + sn * 17 + shq * 4];

  for (int rnd = 0; rnd < 16; ++rnd) {
    const int m0 = mstart + rnd * 16;
    // K A-frag (rows m0+ci, both d halves), shared by all 4 n-subtiles
    const __bf16* kp = Kh + (size_t)(m0 + ci) * 64;
    bf16x8 ka = *(const bf16x8*)(kp + g * 8);
    bf16x8 kb = *(const bf16x8*)(kp + 32 + g * 8);
#pragma unroll
    for (int p = 0; p < 4; ++p) {
      // ---- phase p: scores for nsub p -> weights -> W2[p&1] ----
      f32x4 s = (f32x4){0.f, 0.f, 0.f, 0.f};
      s = __builtin_amdgcn_mfma_f32_16x16x32_bf16(ka, qf[p][0], s, 0, 0, 0);
      s = __builtin_amdgcn_mfma_f32_16x16x32_bf16(kb, qf[p][1], s, 0, 0, 0);
#pragma unroll
      for (int rr = 0; rr < 4; ++rr) {
        float wv = fexp2(s[rr] - C_[p]);
        int m = g * 4 + rr;                    // local m 0..15
        W2[p & 1][m * 272 + ci * 17 + h] = wv;
      }
      __syncthreads();
      // ---- store W2[p&1] (rows n0+p*16..+15, m0..m0+15) — overlaps next compute ----
      {
        size_t wbase = (((size_t)(b * 2048 + n0 + p * 16 + sn)) * 2048 + m0 + sm2) * 16;
        const float* src = (p & 1) ? slds1 : slds0;
        f32x4 v = {src[0], src[1], src[2], src[3]};
        __builtin_nontemporal_store(v, (f32x4*)(Wout + wbase + shq * 4));
      }
    }
  }
}

extern "C" void kernel_launch(void* const* d_in, const int* in_sizes, int n_in,
                              void* d_out, int out_size, void* d_ws, size_t ws_size,
                              hipStream_t stream) {
  const float* queries = (const float*)d_in[0];
  const float* Wq  = (const float*)d_in[1];
  const float* bq  = (const float*)d_in[2];
  const float* Wkv = (const float*)d_in[3];
  const float* bkv = (const float*)d_in[4];
  const float* Wo  = (const float*)d_in[5];
  const float* bo  = (const float*)d_in[6];
  const int Bsz = in_sizes[0] / (2048 * 1024);
  const int M = Bsz * 2048;

  size_t bf16_elems = (size_t)M * 1024 * 5 + (size_t)3072 * 1024 + (size_t)1024 * 1024;
  size_t f32_elems  = (size_t)M * 16 * 2;
  size_t need = bf16_elems * 2 + f32_elems * 4;
  if (ws_size < need) return;

  __bf16* Xbf   = (__bf16*)d_ws;
  __bf16* WcatT = Xbf + (size_t)M * 1024;
  __bf16* WoT   = WcatT + (size_t)3072 * 1024;
  __bf16* Qb    = WoT + (size_t)1024 * 1024;
  __bf16* Kb    = Qb + (size_t)M * 1024;
  __bf16* Vb    = Kb + (size_t)M * 1024;     // Vt [b][h][d][s]
  __bf16* Ob    = Vb + (size_t)M * 1024;
  float*  Smax  = (float*)(Ob + (size_t)M * 1024);
  float*  Sinv  = Smax + (size_t)M * 16;

  float* outp = (float*)d_out;
  float* wout = outp + (size_t)M * 1024;

  cvt_f32_bf16<<<(M * 1024) / (256 * 8), 256, 0, stream>>>(queries, Xbf, M * 1024);
  transpose_bf16<<<dim3(16, 16), 256, 0, stream>>>(Wq, WcatT, 1024, 1024);
  transpose_bf16<<<dim3(32, 16), 256, 0, stream>>>(Wkv, WcatT + (size_t)1024 * 1024, 1024, 2048);
  transpose_bf16<<<dim3(16, 16), 256, 0, stream>>>(Wo, WoT, 1024, 1024);
  gemm128<0><<<dim3(M / 128, 3072 / 128), 256, 0, stream>>>(
      Xbf, WcatT, M, 3072, 1024, bq, bkv, nullptr, Qb, Kb, Vb);
  statspv_kernel<<<Bsz * 128, 1024, 0, stream>>>(Qb, Kb, Vb, Smax, Sinv, Ob);
  attn_w9<<<Bsz * 256, 1024, 0, stream>>>(Qb, Kb, Smax, Sinv, wout);
  gemm128<1><<<dim3(M / 128, 1024 / 128), 256, 0, stream>>>(
      Ob, WoT, M, 1024, 1024, bo, nullptr, outp, nullptr, nullptr, nullptr);
}

// Round 12
// 329.164 us; speedup vs baseline: 1.1137x; 1.1137x over previous
//
#include <hip/hip_runtime.h>

typedef __bf16 bf16x8 __attribute__((ext_vector_type(8)));
typedef __bf16 bf16x4 __attribute__((ext_vector_type(4)));
typedef __bf16 bf16x2 __attribute__((ext_vector_type(2)));
typedef float f32x4 __attribute__((ext_vector_type(4)));
typedef unsigned int u32;

// Problem constants: B (runtime), S=2048, D=1024, H=16, hd=64
#define QSCALE 0.18033688011112042f  // hd^-0.5 * log2(e), folded into Q
#define WSTRIDE 273                  // W2 row stride (odd mod 32 -> 2-way banks, free)

__device__ __forceinline__ void gld_lds16(const void* gsrc, void* ldst) {
  __builtin_amdgcn_global_load_lds(
      (const __attribute__((address_space(1))) u32*)gsrc,
      (__attribute__((address_space(3))) u32*)ldst, 16, 0, 0);
}

__device__ __forceinline__ float fexp2(float x) {
#if __has_builtin(__builtin_amdgcn_exp2f)
  return __builtin_amdgcn_exp2f(x);
#else
  return exp2f(x);
#endif
}

__device__ __forceinline__ u32 pkbf(float a, float b) {
  bf16x2 t; t[0] = (__bf16)a; t[1] = (__bf16)b;
  return __builtin_bit_cast(u32, t);
}

// ---------------- fp32 -> bf16 elementwise convert ----------------
__global__ __launch_bounds__(256) void cvt_f32_bf16(const float* __restrict__ src,
                                                    __bf16* __restrict__ dst, int n) {
  int i = (blockIdx.x * 256 + threadIdx.x) * 8;
  if (i >= n) return;
  const float4* p = (const float4*)(src + i);
  float4 a = p[0], b = p[1];
  bf16x8 v;
  v[0] = (__bf16)a.x; v[1] = (__bf16)a.y; v[2] = (__bf16)a.z; v[3] = (__bf16)a.w;
  v[4] = (__bf16)b.x; v[5] = (__bf16)b.y; v[6] = (__bf16)b.z; v[7] = (__bf16)b.w;
  *(bf16x8*)(dst + i) = v;
}

// ---------------- transpose fp32[R][C] -> bf16[C][R] ----------------
__global__ __launch_bounds__(256) void transpose_bf16(const float* __restrict__ src,
                                                      __bf16* __restrict__ dst, int R, int C) {
  __shared__ float tile[64 * 65];
  int c0 = blockIdx.x * 64, r0 = blockIdx.y * 64;
  int t = threadIdx.x;
  for (int i = 0; i < 16; ++i) {
    int idx = t + i * 256; int rr = idx >> 6, cc = idx & 63;
    tile[rr * 65 + cc] = src[(size_t)(r0 + rr) * C + (c0 + cc)];
  }
  __syncthreads();
  for (int i = 0; i < 16; ++i) {
    int idx = t + i * 256; int cc = idx >> 6, rr = idx & 63;
    dst[(size_t)(c0 + cc) * R + (r0 + rr)] = (__bf16)tile[rr * 65 + cc];
  }
}

// ---------------- 128x128-tile bf16 MFMA GEMM, A[M][K] @ Bt[N][K]^T ----------------
template<int EPI>
__global__ __launch_bounds__(256) void gemm128(
    const __bf16* __restrict__ A, const __bf16* __restrict__ Bt,
    int M, int N, int K,
    const float* __restrict__ bias0, const float* __restrict__ bias1,
    float* __restrict__ outf,
    __bf16* __restrict__ Qo, __bf16* __restrict__ Ko, __bf16* __restrict__ Vt)
{
  __shared__ __bf16 As[128 * 32];
  __shared__ __bf16 Bs[128 * 32];
  const int m0 = blockIdx.x * 128, n0 = blockIdx.y * 128;
  const int t = threadIdx.x, lane = t & 63, wave = t >> 6;
  const int wr = wave >> 1, wc = wave & 1;
  const int g = lane >> 4, ci = lane & 15;
  f32x4 acc[4][4];
#pragma unroll
  for (int i = 0; i < 4; ++i)
#pragma unroll
    for (int j = 0; j < 4; ++j) acc[i][j] = (f32x4){0.f, 0.f, 0.f, 0.f};

  const char* Ab = (const char*)A;
  const char* Bb = (const char*)Bt;
  for (int k0 = 0; k0 < K; k0 += 32) {
#pragma unroll
    for (int i = 0; i < 2; ++i) {
      int o = wave * 2048 + i * 1024 + lane * 16;
      int row = o >> 6, cb = o & 63;
      gld_lds16(Ab + ((size_t)(m0 + row) * K + k0) * 2 + cb, (char*)As + o);
      gld_lds16(Bb + ((size_t)(n0 + row) * K + k0) * 2 + cb, (char*)Bs + o);
    }
    __syncthreads();
    bf16x8 af[4], bfr[4];
#pragma unroll
    for (int i = 0; i < 4; ++i)
      af[i] = *(const bf16x8*)((const char*)As + (wr * 64 + i * 16 + ci) * 64 + g * 16);
#pragma unroll
    for (int j = 0; j < 4; ++j)
      bfr[j] = *(const bf16x8*)((const char*)Bs + (wc * 64 + j * 16 + ci) * 64 + g * 16);
#pragma unroll
    for (int i = 0; i < 4; ++i)
#pragma unroll
      for (int j = 0; j < 4; ++j)
        acc[i][j] = __builtin_amdgcn_mfma_f32_16x16x32_bf16(af[i], bfr[j], acc[i][j], 0, 0, 0);
    __syncthreads();
  }
#pragma unroll
  for (int j = 0; j < 4; ++j) {
    int c = n0 + wc * 64 + j * 16 + ci;
    float bias;
    if (EPI == 0) bias = (c < 1024) ? bias0[c] : bias1[c - 1024];
    else          bias = bias0[c];
#pragma unroll
    for (int i = 0; i < 4; ++i) {
      int rbase = m0 + wr * 64 + i * 16 + g * 4;
      if (EPI == 1) {
#pragma unroll
        for (int r = 0; r < 4; ++r)
          outf[(size_t)(rbase + r) * 1024 + c] = acc[i][j][r] + bias;
      } else {
        int b = rbase >> 11, n = rbase & 2047;
        if (c < 1024) {
          int h = c >> 6, d = c & 63;
#pragma unroll
          for (int r = 0; r < 4; ++r)
            Qo[(((size_t)(b * 16 + h)) * 2048 + n + r) * 64 + d] =
                (__bf16)((acc[i][j][r] + bias) * QSCALE);
        } else if (c < 2048) {
          int c2 = c - 1024; int h = c2 >> 6, d = c2 & 63;
#pragma unroll
          for (int r = 0; r < 4; ++r)
            Ko[(((size_t)(b * 16 + h)) * 2048 + n + r) * 64 + d] =
                (__bf16)(acc[i][j][r] + bias);
        } else {
          int c2 = c - 2048; int h = c2 >> 6, d = c2 & 63;
          bf16x4 pk;
#pragma unroll
          for (int r = 0; r < 4; ++r) pk[r] = (__bf16)(acc[i][j][r] + bias);
          *(bf16x4*)(Vt + ((size_t)(b * 16 + h) * 64 + d) * 2048 + n) = pk;
        }
      }
    }
  }
}

// ---------------- statspv: softmax stats + flash PV (O single-writer) ----------------
// [validated R9: K double-buffered, one barrier/round; stats row mapping via shuffles]
__global__ __launch_bounds__(1024) void statspv_kernel(
    const __bf16* __restrict__ Q, const __bf16* __restrict__ K, const __bf16* __restrict__ Vt,
    float* __restrict__ Smax, float* __restrict__ Sinv, __bf16* __restrict__ Ob)
{
  __shared__ __bf16 Kl[2][128 * 64]; // [m128][d64], chunk c stored at c^(m&7); dbuf
  __shared__ __bf16 Pp[16][16][40];  // per-wave P patch: [wave][n16][40] (80B rows)
  const int blk = blockIdx.x;
  const int b = blk >> 7, rem = blk & 127;
  const int h = rem >> 3, ns8 = rem & 7;
  const int w = threadIdx.x >> 6, lane = threadIdx.x & 63;
  const int g = lane >> 4, ci = lane & 15;
  const size_t bh = (size_t)(b * 16 + h);
  const __bf16* Qh = Q + bh * 2048 * 64;
  const __bf16* Kh = K + bh * 2048 * 64;
  const __bf16* Vh = Vt + bh * 64 * 2048;   // [d][s]
  const int n0 = ns8 * 256 + w * 16;

  bf16x8 qf0 = *(const bf16x8*)(Qh + (size_t)(n0 + ci) * 64 + g * 8);
  bf16x8 qf1 = *(const bf16x8*)(Qh + (size_t)(n0 + ci) * 64 + 32 + g * 8);

  const int so = threadIdx.x * 16;
  const int sm = so >> 7;
  const int sc = ((so >> 4) & 7) ^ (sm & 7);

  float rm = -3.0e30f, rs = 0.f;
  f32x4 oacc[4];
#pragma unroll
  for (int fd = 0; fd < 4; ++fd) oacc[fd] = (f32x4){0.f, 0.f, 0.f, 0.f};

  // prologue: stage tile 0
  gld_lds16(Kh + ((size_t)sm) * 64 + sc * 8, (char*)Kl[0] + so);
  __syncthreads();
  int cur = 0;

  for (int mt = 0; mt < 2048; mt += 128) {
    // issue next tile's stage FIRST (hides under this tile's compute)
    if (mt + 128 < 2048)
      gld_lds16(Kh + ((size_t)(mt + 128 + sm)) * 64 + sc * 8, (char*)Kl[cur ^ 1] + so);
    const char* Kc = (const char*)Kl[cur];
    f32x4 st[8];
#pragma unroll
    for (int fm = 0; fm < 8; ++fm) {
      int row = fm * 16 + ci;
      bf16x8 ka = *(const bf16x8*)(Kc + row * 128 + ((g ^ (ci & 7)) * 16));
      bf16x8 kb = *(const bf16x8*)(Kc + row * 128 + (((4 + g) ^ (ci & 7)) * 16));
      st[fm] = (f32x4){0.f, 0.f, 0.f, 0.f};
      st[fm] = __builtin_amdgcn_mfma_f32_16x16x32_bf16(ka, qf0, st[fm], 0, 0, 0);
      st[fm] = __builtin_amdgcn_mfma_f32_16x16x32_bf16(kb, qf1, st[fm], 0, 0, 0);
    }
    // per-round row max for col n=ci (cross-g combine so all 4 g-lanes agree)
    float tm = -3.0e30f;
#pragma unroll
    for (int fm = 0; fm < 8; ++fm)
#pragma unroll
      for (int r = 0; r < 4; ++r) tm = fmaxf(tm, st[fm][r]);
    tm = fmaxf(tm, __shfl_xor(tm, 16, 64));
    tm = fmaxf(tm, __shfl_xor(tm, 32, 64));
    float nm = fmaxf(rm, tm);
    float scale = fexp2(rm - nm);       // scale for row n = ci
    rs *= scale;
    // oacc rows are n = g*4+r -> fetch those rows' scales from lanes g*4+r
    f32x4 rsc;
#pragma unroll
    for (int r = 0; r < 4; ++r) rsc[r] = __shfl(scale, g * 4 + r, 64);
#pragma unroll
    for (int fd = 0; fd < 4; ++fd)
#pragma unroll
      for (int r = 0; r < 4; ++r) oacc[fd][r] *= rsc[r];
    rm = nm;
    // PV + sum, one 32-m slice at a time (P bf16 patch, validated layout)
    float ts = 0.f;
#pragma unroll
    for (int kk2 = 0; kk2 < 4; ++kk2) {
#pragma unroll
      for (int fm2 = 0; fm2 < 2; ++fm2) {
        f32x4 s = st[kk2 * 2 + fm2];
        f32x4 wv;
#pragma unroll
        for (int r = 0; r < 4; ++r) { wv[r] = fexp2(s[r] - nm); ts += wv[r]; }
        u32* pb = (u32*)((char*)&Pp[w][ci][0] + (fm2 * 8 + g * 2) * 4);
        pb[0] = pkbf(wv[0], wv[1]);
        pb[1] = pkbf(wv[2], wv[3]);
      }
      bf16x8 pa = *(const bf16x8*)((const char*)&Pp[w][ci][0] + g * 16);
#pragma unroll
      for (int fd = 0; fd < 4; ++fd) {
        bf16x8 vf = *(const bf16x8*)(Vh + (size_t)(fd * 16 + ci) * 2048 +
                                     mt + kk2 * 32 + g * 8);
        oacc[fd] = __builtin_amdgcn_mfma_f32_16x16x32_bf16(pa, vf, oacc[fd], 0, 0, 0);
      }
    }
    rs += ts;
    __syncthreads();
    cur ^= 1;
  }
  // combine per-lane partial sums across the 4 g-groups (rm already common)
#pragma unroll
  for (int off = 16; off <= 32; off <<= 1) {
    float om = __shfl_xor(rm, off, 64);
    float os = __shfl_xor(rs, off, 64);
    float nm = fmaxf(rm, om);
    rs = rs * fexp2(rm - nm) + os * fexp2(om - nm);
    rm = nm;
  }
  const float inv = 1.0f / rs;          // for row n = ci
  if (lane < 16) {
    size_t idx = bh * 2048 + n0 + ci;
    Smax[idx] = rm;
    Sinv[idx] = inv;
  }
  // O write rows are n = g*4+r -> fetch those rows' inv from lanes g*4+r
  f32x4 rinv;
#pragma unroll
  for (int r = 0; r < 4; ++r) rinv[r] = __shfl(inv, g * 4 + r, 64);
#pragma unroll
  for (int fd = 0; fd < 4; ++fd)
#pragma unroll
    for (int r = 0; r < 4; ++r) {
      int n = n0 + g * 4 + r;
      Ob[((size_t)(b * 2048 + n)) * 1024 + h * 64 + fd * 16 + ci] =
          (__bf16)(oacc[fd][r] * rinv[r]);
    }
}

// ---------------- weights-only kernel (v12 = R9 structure + odd W2 stride) ----------------
// Block = (b, n-tile 32, m-quarter 512); 16 waves = 16 heads; grid = B*256.
// 2 blocks/CU (LDS 2x34.9KB x 2 blocks = 139.8KB).
// v12 change vs R9: W2 row stride 272 -> 273 words (mod 32 = 17, odd).
//   write banks: (4g + 17ci + h) mod 32 -> 64 lanes cover 32 banks 2x (free).
//   store-read banks: (17m + 4hq + j) -> 2-way (free).  Was 4-way both sides.
// Per round (32 m): load K frags once (shared by both 16-row n-subtiles);
//   compute nsub0 -> W2[0]; bar; {store W2[0] || compute nsub1 -> W2[1]}; bar;
//   {store W2[1] || next round}. Buffer reuse always >= 1 barrier away.
__global__ __launch_bounds__(1024, 8) void attn_w7(
    const __bf16* __restrict__ Q, const __bf16* __restrict__ K,
    const float* __restrict__ Smax, const float* __restrict__ Sinv,
    float* __restrict__ Wout)
{
  __shared__ float W2[2][32 * WSTRIDE];   // 2 x 34.9 KB (nsub ping-pong)
  // bijective XCD swizzle: each XCD gets a contiguous 64-block chunk = one (b, mq)
  const int nwg = gridDim.x, cpx = nwg >> 3;
  const int o = blockIdx.x;
  const int blk = (o & 7) * cpx + (o >> 3);
  const int b = blk >> 8, r = blk & 255;
  const int mq = r >> 6, nt = r & 63;
  const int n0 = nt * 32, mstart = mq * 512;
  const int h = threadIdx.x >> 6;            // wave = head
  const int lane = threadIdx.x & 63;
  const int g = lane >> 4, ci = lane & 15;
  const size_t bh = (size_t)(b * 16 + h);
  const __bf16* Qh = Q + bh * 2048 * 64;
  const __bf16* Kh = K + bh * 2048 * 64;

  float sm_[2], si_[2];
  bf16x8 qf[2][2];
#pragma unroll
  for (int nsub = 0; nsub < 2; ++nsub) {
    size_t idx = bh * 2048 + n0 + nsub * 16 + ci;
    sm_[nsub] = Smax[idx];
    si_[nsub] = Sinv[idx];
    const __bf16* qp = Qh + (size_t)(n0 + nsub * 16 + ci) * 64;
    qf[nsub][0] = *(const bf16x8*)(qp + g * 8);
    qf[nsub][1] = *(const bf16x8*)(qp + 32 + g * 8);
  }

  for (int rnd = 0; rnd < 16; ++rnd) {
    const int m0 = mstart + rnd * 32;
    // K A-frags (row=m=ci, k=d), shared by both n-subtiles
    bf16x8 ka[2], kb[2];
#pragma unroll
    for (int fm = 0; fm < 2; ++fm) {
      const __bf16* kp = Kh + (size_t)(m0 + fm * 16 + ci) * 64;
      ka[fm] = *(const bf16x8*)(kp + g * 8);
      kb[fm] = *(const bf16x8*)(kp + 32 + g * 8);
    }
    // ---- nsub 0: scores -> weights -> W2[0] ----
#pragma unroll
    for (int fm = 0; fm < 2; ++fm) {
      f32x4 s = (f32x4){0.f, 0.f, 0.f, 0.f};
      s = __builtin_amdgcn_mfma_f32_16x16x32_bf16(ka[fm], qf[0][0], s, 0, 0, 0);
      s = __builtin_amdgcn_mfma_f32_16x16x32_bf16(kb[fm], qf[0][1], s, 0, 0, 0);
#pragma unroll
      for (int r = 0; r < 4; ++r) {
        float wv = fexp2(s[r] - sm_[0]) * si_[0];
        int m = fm * 16 + g * 4 + r;
        W2[0][m * WSTRIDE + ci * 17 + h] = wv;
      }
    }
    __syncthreads();
    // ---- store W2[0] (rows n0..n0+15) overlapped with nsub 1 compute ----
    {
      size_t wbase = (((size_t)(b * 2048 + n0)) * 2048 + m0) * 16;
#pragma unroll
      for (int it = 0; it < 2; ++it) {
        int slot = threadIdx.x + it * 1024;       // slot = n*128 + m*4 + hq
        int n = slot >> 7, m = (slot >> 2) & 31, hq = slot & 3;
        const float* src = &W2[0][m * WSTRIDE + n * 17 + hq * 4];
        f32x4 v = {src[0], src[1], src[2], src[3]};
        __builtin_nontemporal_store(
            v, (f32x4*)(Wout + wbase + ((size_t)n * 2048 + m) * 16 + hq * 4));
      }
    }
#pragma unroll
    for (int fm = 0; fm < 2; ++fm) {
      f32x4 s = (f32x4){0.f, 0.f, 0.f, 0.f};
      s = __builtin_amdgcn_mfma_f32_16x16x32_bf16(ka[fm], qf[1][0], s, 0, 0, 0);
      s = __builtin_amdgcn_mfma_f32_16x16x32_bf16(kb[fm], qf[1][1], s, 0, 0, 0);
#pragma unroll
      for (int r = 0; r < 4; ++r) {
        float wv = fexp2(s[r] - sm_[1]) * si_[1];
        int m = fm * 16 + g * 4 + r;
        W2[1][m * WSTRIDE + ci * 17 + h] = wv;
      }
    }
    __syncthreads();
    // ---- store W2[1] (rows n0+16..n0+31) overlapped with next round ----
    {
      size_t wbase = (((size_t)(b * 2048 + n0 + 16)) * 2048 + m0) * 16;
#pragma unroll
      for (int it = 0; it < 2; ++it) {
        int slot = threadIdx.x + it * 1024;
        int n = slot >> 7, m = (slot >> 2) & 31, hq = slot & 3;
        const float* src = &W2[1][m * WSTRIDE + n * 17 + hq * 4];
        f32x4 v = {src[0], src[1], src[2], src[3]};
        __builtin_nontemporal_store(
            v, (f32x4*)(Wout + wbase + ((size_t)n * 2048 + m) * 16 + hq * 4));
      }
    }
  }
}

extern "C" void kernel_launch(void* const* d_in, const int* in_sizes, int n_in,
                              void* d_out, int out_size, void* d_ws, size_t ws_size,
                              hipStream_t stream) {
  const float* queries = (const float*)d_in[0];
  const float* Wq  = (const float*)d_in[1];
  const float* bq  = (const float*)d_in[2];
  const float* Wkv = (const float*)d_in[3];
  const float* bkv = (const float*)d_in[4];
  const float* Wo  = (const float*)d_in[5];
  const float* bo  = (const float*)d_in[6];
  const int Bsz = in_sizes[0] / (2048 * 1024);
  const int M = Bsz * 2048;

  size_t bf16_elems = (size_t)M * 1024 * 5 + (size_t)3072 * 1024 + (size_t)1024 * 1024;
  size_t f32_elems  = (size_t)M * 16 * 2;
  size_t need = bf16_elems * 2 + f32_elems * 4;
  if (ws_size < need) return;

  __bf16* Xbf   = (__bf16*)d_ws;
  __bf16* WcatT = Xbf + (size_t)M * 1024;
  __bf16* WoT   = WcatT + (size_t)3072 * 1024;
  __bf16* Qb    = WoT + (size_t)1024 * 1024;
  __bf16* Kb    = Qb + (size_t)M * 1024;
  __bf16* Vb    = Kb + (size_t)M * 1024;     // Vt [b][h][d][s]
  __bf16* Ob    = Vb + (size_t)M * 1024;
  float*  Smax  = (float*)(Ob + (size_t)M * 1024);
  float*  Sinv  = Smax + (size_t)M * 16;

  float* outp = (float*)d_out;
  float* wout = outp + (size_t)M * 1024;

  cvt_f32_bf16<<<(M * 1024) / (256 * 8), 256, 0, stream>>>(queries, Xbf, M * 1024);
  transpose_bf16<<<dim3(16, 16), 256, 0, stream>>>(Wq, WcatT, 1024, 1024);
  transpose_bf16<<<dim3(32, 16), 256, 0, stream>>>(Wkv, WcatT + (size_t)1024 * 1024, 1024, 2048);
  transpose_bf16<<<dim3(16, 16), 256, 0, stream>>>(Wo, WoT, 1024, 1024);
  gemm128<0><<<dim3(M / 128, 3072 / 128), 256, 0, stream>>>(
      Xbf, WcatT, M, 3072, 1024, bq, bkv, nullptr, Qb, Kb, Vb);
  statspv_kernel<<<Bsz * 128, 1024, 0, stream>>>(Qb, Kb, Vb, Smax, Sinv, Ob);
  attn_w7<<<Bsz * 256, 1024, 0, stream>>>(Qb, Kb, Smax, Sinv, wout);
  gemm128<1><<<dim3(M / 128, 1024 / 128), 256, 0, stream>>>(
      Ob, WoT, M, 1024, 1024, bo, nullptr, outp, nullptr, nullptr, nullptr);
}

// Round 13
// 325.694 us; speedup vs baseline: 1.1256x; 1.0107x over previous
//
#include <hip/hip_runtime.h>

typedef __bf16 bf16x8 __attribute__((ext_vector_type(8)));
typedef __bf16 bf16x4 __attribute__((ext_vector_type(4)));
typedef __bf16 bf16x2 __attribute__((ext_vector_type(2)));
typedef float f32x4 __attribute__((ext_vector_type(4)));
typedef unsigned int u32;

// Problem constants: B (runtime), S=2048, D=1024, H=16, hd=64
#define QSCALE 0.18033688011112042f  // hd^-0.5 * log2(e), folded into Q
#define WSTRIDE 273                  // W2 row stride (odd mod 32 -> 2-way banks, free)

__device__ __forceinline__ void gld_lds16(const void* gsrc, void* ldst) {
  __builtin_amdgcn_global_load_lds(
      (const __attribute__((address_space(1))) u32*)gsrc,
      (__attribute__((address_space(3))) u32*)ldst, 16, 0, 0);
}

__device__ __forceinline__ float fexp2(float x) {
#if __has_builtin(__builtin_amdgcn_exp2f)
  return __builtin_amdgcn_exp2f(x);
#else
  return exp2f(x);
#endif
}

__device__ __forceinline__ u32 pkbf(float a, float b) {
  bf16x2 t; t[0] = (__bf16)a; t[1] = (__bf16)b;
  return __builtin_bit_cast(u32, t);
}

// ---------------- fp32 -> bf16 elementwise convert ----------------
__global__ __launch_bounds__(256) void cvt_f32_bf16(const float* __restrict__ src,
                                                    __bf16* __restrict__ dst, int n) {
  int i = (blockIdx.x * 256 + threadIdx.x) * 8;
  if (i >= n) return;
  const float4* p = (const float4*)(src + i);
  float4 a = p[0], b = p[1];
  bf16x8 v;
  v[0] = (__bf16)a.x; v[1] = (__bf16)a.y; v[2] = (__bf16)a.z; v[3] = (__bf16)a.w;
  v[4] = (__bf16)b.x; v[5] = (__bf16)b.y; v[6] = (__bf16)b.z; v[7] = (__bf16)b.w;
  *(bf16x8*)(dst + i) = v;
}

// ---------------- transpose fp32[R][C] -> bf16[C][R] ----------------
__global__ __launch_bounds__(256) void transpose_bf16(const float* __restrict__ src,
                                                      __bf16* __restrict__ dst, int R, int C) {
  __shared__ float tile[64 * 65];
  int c0 = blockIdx.x * 64, r0 = blockIdx.y * 64;
  int t = threadIdx.x;
  for (int i = 0; i < 16; ++i) {
    int idx = t + i * 256; int rr = idx >> 6, cc = idx & 63;
    tile[rr * 65 + cc] = src[(size_t)(r0 + rr) * C + (c0 + cc)];
  }
  __syncthreads();
  for (int i = 0; i < 16; ++i) {
    int idx = t + i * 256; int cc = idx >> 6, rr = idx & 63;
    dst[(size_t)(c0 + cc) * R + (r0 + rr)] = (__bf16)tile[rr * 65 + cc];
  }
}

// ---------------- 128x128-tile bf16 MFMA GEMM, A[M][K] @ Bt[N][K]^T ----------------
template<int EPI>
__global__ __launch_bounds__(256) void gemm128(
    const __bf16* __restrict__ A, const __bf16* __restrict__ Bt,
    int M, int N, int K,
    const float* __restrict__ bias0, const float* __restrict__ bias1,
    float* __restrict__ outf,
    __bf16* __restrict__ Qo, __bf16* __restrict__ Ko, __bf16* __restrict__ Vt)
{
  __shared__ __bf16 As[128 * 32];
  __shared__ __bf16 Bs[128 * 32];
  const int m0 = blockIdx.x * 128, n0 = blockIdx.y * 128;
  const int t = threadIdx.x, lane = t & 63, wave = t >> 6;
  const int wr = wave >> 1, wc = wave & 1;
  const int g = lane >> 4, ci = lane & 15;
  f32x4 acc[4][4];
#pragma unroll
  for (int i = 0; i < 4; ++i)
#pragma unroll
    for (int j = 0; j < 4; ++j) acc[i][j] = (f32x4){0.f, 0.f, 0.f, 0.f};

  const char* Ab = (const char*)A;
  const char* Bb = (const char*)Bt;
  for (int k0 = 0; k0 < K; k0 += 32) {
#pragma unroll
    for (int i = 0; i < 2; ++i) {
      int o = wave * 2048 + i * 1024 + lane * 16;
      int row = o >> 6, cb = o & 63;
      gld_lds16(Ab + ((size_t)(m0 + row) * K + k0) * 2 + cb, (char*)As + o);
      gld_lds16(Bb + ((size_t)(n0 + row) * K + k0) * 2 + cb, (char*)Bs + o);
    }
    __syncthreads();
    bf16x8 af[4], bfr[4];
#pragma unroll
    for (int i = 0; i < 4; ++i)
      af[i] = *(const bf16x8*)((const char*)As + (wr * 64 + i * 16 + ci) * 64 + g * 16);
#pragma unroll
    for (int j = 0; j < 4; ++j)
      bfr[j] = *(const bf16x8*)((const char*)Bs + (wc * 64 + j * 16 + ci) * 64 + g * 16);
#pragma unroll
    for (int i = 0; i < 4; ++i)
#pragma unroll
      for (int j = 0; j < 4; ++j)
        acc[i][j] = __builtin_amdgcn_mfma_f32_16x16x32_bf16(af[i], bfr[j], acc[i][j], 0, 0, 0);
    __syncthreads();
  }
#pragma unroll
  for (int j = 0; j < 4; ++j) {
    int c = n0 + wc * 64 + j * 16 + ci;
    float bias;
    if (EPI == 0) bias = (c < 1024) ? bias0[c] : bias1[c - 1024];
    else          bias = bias0[c];
#pragma unroll
    for (int i = 0; i < 4; ++i) {
      int rbase = m0 + wr * 64 + i * 16 + g * 4;
      if (EPI == 1) {
#pragma unroll
        for (int r = 0; r < 4; ++r)
          outf[(size_t)(rbase + r) * 1024 + c] = acc[i][j][r] + bias;
      } else {
        int b = rbase >> 11, n = rbase & 2047;
        if (c < 1024) {
          int h = c >> 6, d = c & 63;
#pragma unroll
          for (int r = 0; r < 4; ++r)
            Qo[(((size_t)(b * 16 + h)) * 2048 + n + r) * 64 + d] =
                (__bf16)((acc[i][j][r] + bias) * QSCALE);
        } else if (c < 2048) {
          int c2 = c - 1024; int h = c2 >> 6, d = c2 & 63;
#pragma unroll
          for (int r = 0; r < 4; ++r)
            Ko[(((size_t)(b * 16 + h)) * 2048 + n + r) * 64 + d] =
                (__bf16)(acc[i][j][r] + bias);
        } else {
          int c2 = c - 2048; int h = c2 >> 6, d = c2 & 63;
          bf16x4 pk;
#pragma unroll
          for (int r = 0; r < 4; ++r) pk[r] = (__bf16)(acc[i][j][r] + bias);
          *(bf16x4*)(Vt + ((size_t)(b * 16 + h) * 64 + d) * 2048 + n) = pk;
        }
      }
    }
  }
}

// ---------------- statspv: softmax stats + flash PV (O single-writer) ----------------
// v13: 512-thread blocks (8 waves = 8 n-subtiles = 128 n-rows), grid Bsz*256 ->
// 2 blocks/CU (launch_bounds(512,4): VGPR<=128; LDS 42KB x2 = 84KB). While one
// block drains its round barrier (stage vmcnt + lgkmcnt), the other computes.
// All per-wave math byte-identical to R9/R12-validated version; only the block
// decode and the (now 2-issue) K-stage loop changed. K total read doubles
// (67->134MB grid-wide) — negligible vs per-CU port budget.
__global__ __launch_bounds__(512, 4) void statspv_kernel(
    const __bf16* __restrict__ Q, const __bf16* __restrict__ K, const __bf16* __restrict__ Vt,
    float* __restrict__ Smax, float* __restrict__ Sinv, __bf16* __restrict__ Ob)
{
  __shared__ __bf16 Kl[2][128 * 64]; // [m128][d64], chunk c stored at c^(m&7); dbuf
  __shared__ __bf16 Pp[8][16][40];   // per-wave P patch: [wave][n16][40] (80B rows)
  const int blk = blockIdx.x;
  const int b = blk >> 8, rem = blk & 255;
  const int h = rem >> 4, nsx = rem & 15;
  const int w = threadIdx.x >> 6, lane = threadIdx.x & 63;
  const int g = lane >> 4, ci = lane & 15;
  const size_t bh = (size_t)(b * 16 + h);
  const __bf16* Qh = Q + bh * 2048 * 64;
  const __bf16* Kh = K + bh * 2048 * 64;
  const __bf16* Vh = Vt + bh * 64 * 2048;   // [d][s]
  const int n0 = nsx * 128 + w * 16;

  bf16x8 qf0 = *(const bf16x8*)(Qh + (size_t)(n0 + ci) * 64 + g * 8);
  bf16x8 qf1 = *(const bf16x8*)(Qh + (size_t)(n0 + ci) * 64 + 32 + g * 8);

  // stage decode: 512 threads x 16B x 2 issues = 16KB tile
  const int so0 = threadIdx.x * 16;
  const int so1 = so0 + 512 * 16;
  const int sm0 = so0 >> 7, sc0 = ((so0 >> 4) & 7) ^ (sm0 & 7);
  const int sm1 = so1 >> 7, sc1 = ((so1 >> 4) & 7) ^ (sm1 & 7);

  float rm = -3.0e30f, rs = 0.f;
  f32x4 oacc[4];
#pragma unroll
  for (int fd = 0; fd < 4; ++fd) oacc[fd] = (f32x4){0.f, 0.f, 0.f, 0.f};

  // prologue: stage tile 0
  gld_lds16(Kh + ((size_t)sm0) * 64 + sc0 * 8, (char*)Kl[0] + so0);
  gld_lds16(Kh + ((size_t)sm1) * 64 + sc1 * 8, (char*)Kl[0] + so1);
  __syncthreads();
  int cur = 0;

  for (int mt = 0; mt < 2048; mt += 128) {
    // issue next tile's stage FIRST (hides under this tile's compute)
    if (mt + 128 < 2048) {
      gld_lds16(Kh + ((size_t)(mt + 128 + sm0)) * 64 + sc0 * 8, (char*)Kl[cur ^ 1] + so0);
      gld_lds16(Kh + ((size_t)(mt + 128 + sm1)) * 64 + sc1 * 8, (char*)Kl[cur ^ 1] + so1);
    }
    const char* Kc = (const char*)Kl[cur];
    f32x4 st[8];
#pragma unroll
    for (int fm = 0; fm < 8; ++fm) {
      int row = fm * 16 + ci;
      bf16x8 ka = *(const bf16x8*)(Kc + row * 128 + ((g ^ (ci & 7)) * 16));
      bf16x8 kb = *(const bf16x8*)(Kc + row * 128 + (((4 + g) ^ (ci & 7)) * 16));
      st[fm] = (f32x4){0.f, 0.f, 0.f, 0.f};
      st[fm] = __builtin_amdgcn_mfma_f32_16x16x32_bf16(ka, qf0, st[fm], 0, 0, 0);
      st[fm] = __builtin_amdgcn_mfma_f32_16x16x32_bf16(kb, qf1, st[fm], 0, 0, 0);
    }
    // per-round row max for col n=ci (cross-g combine so all 4 g-lanes agree)
    float tm = -3.0e30f;
#pragma unroll
    for (int fm = 0; fm < 8; ++fm)
#pragma unroll
      for (int r = 0; r < 4; ++r) tm = fmaxf(tm, st[fm][r]);
    tm = fmaxf(tm, __shfl_xor(tm, 16, 64));
    tm = fmaxf(tm, __shfl_xor(tm, 32, 64));
    float nm = fmaxf(rm, tm);
    float scale = fexp2(rm - nm);       // scale for row n = ci
    rs *= scale;
    // oacc rows are n = g*4+r -> fetch those rows' scales from lanes g*4+r
    f32x4 rsc;
#pragma unroll
    for (int r = 0; r < 4; ++r) rsc[r] = __shfl(scale, g * 4 + r, 64);
#pragma unroll
    for (int fd = 0; fd < 4; ++fd)
#pragma unroll
      for (int r = 0; r < 4; ++r) oacc[fd][r] *= rsc[r];
    rm = nm;
    // PV + sum, one 32-m slice at a time (P bf16 patch, validated layout)
    float ts = 0.f;
#pragma unroll
    for (int kk2 = 0; kk2 < 4; ++kk2) {
#pragma unroll
      for (int fm2 = 0; fm2 < 2; ++fm2) {
        f32x4 s = st[kk2 * 2 + fm2];
        f32x4 wv;
#pragma unroll
        for (int r = 0; r < 4; ++r) { wv[r] = fexp2(s[r] - nm); ts += wv[r]; }
        u32* pb = (u32*)((char*)&Pp[w][ci][0] + (fm2 * 8 + g * 2) * 4);
        pb[0] = pkbf(wv[0], wv[1]);
        pb[1] = pkbf(wv[2], wv[3]);
      }
      bf16x8 pa = *(const bf16x8*)((const char*)&Pp[w][ci][0] + g * 16);
#pragma unroll
      for (int fd = 0; fd < 4; ++fd) {
        bf16x8 vf = *(const bf16x8*)(Vh + (size_t)(fd * 16 + ci) * 2048 +
                                     mt + kk2 * 32 + g * 8);
        oacc[fd] = __builtin_amdgcn_mfma_f32_16x16x32_bf16(pa, vf, oacc[fd], 0, 0, 0);
      }
    }
    rs += ts;
    __syncthreads();
    cur ^= 1;
  }
  // combine per-lane partial sums across the 4 g-groups (rm already common)
#pragma unroll
  for (int off = 16; off <= 32; off <<= 1) {
    float om = __shfl_xor(rm, off, 64);
    float os = __shfl_xor(rs, off, 64);
    float nm = fmaxf(rm, om);
    rs = rs * fexp2(rm - nm) + os * fexp2(om - nm);
    rm = nm;
  }
  const float inv = 1.0f / rs;          // for row n = ci
  if (lane < 16) {
    size_t idx = bh * 2048 + n0 + ci;
    Smax[idx] = rm;
    Sinv[idx] = inv;
  }
  // O write rows are n = g*4+r -> fetch those rows' inv from lanes g*4+r
  f32x4 rinv;
#pragma unroll
  for (int r = 0; r < 4; ++r) rinv[r] = __shfl(inv, g * 4 + r, 64);
#pragma unroll
  for (int fd = 0; fd < 4; ++fd)
#pragma unroll
    for (int r = 0; r < 4; ++r) {
      int n = n0 + g * 4 + r;
      Ob[((size_t)(b * 2048 + n)) * 1024 + h * 64 + fd * 16 + ci] =
          (__bf16)(oacc[fd][r] * rinv[r]);
    }
}

// ---------------- weights-only kernel (v12 = R9 structure + odd W2 stride) ----------------
// [validated R12] Block = (b, n-tile 32, m-quarter 512); 16 waves = 16 heads;
// grid = B*256; 2 blocks/CU.
__global__ __launch_bounds__(1024, 8) void attn_w7(
    const __bf16* __restrict__ Q, const __bf16* __restrict__ K,
    const float* __restrict__ Smax, const float* __restrict__ Sinv,
    float* __restrict__ Wout)
{
  __shared__ float W2[2][32 * WSTRIDE];   // 2 x 34.9 KB (nsub ping-pong)
  // bijective XCD swizzle: each XCD gets a contiguous 64-block chunk = one (b, mq)
  const int nwg = gridDim.x, cpx = nwg >> 3;
  const int o = blockIdx.x;
  const int blk = (o & 7) * cpx + (o >> 3);
  const int b = blk >> 8, r = blk & 255;
  const int mq = r >> 6, nt = r & 63;
  const int n0 = nt * 32, mstart = mq * 512;
  const int h = threadIdx.x >> 6;            // wave = head
  const int lane = threadIdx.x & 63;
  const int g = lane >> 4, ci = lane & 15;
  const size_t bh = (size_t)(b * 16 + h);
  const __bf16* Qh = Q + bh * 2048 * 64;
  const __bf16* Kh = K + bh * 2048 * 64;

  float sm_[2], si_[2];
  bf16x8 qf[2][2];
#pragma unroll
  for (int nsub = 0; nsub < 2; ++nsub) {
    size_t idx = bh * 2048 + n0 + nsub * 16 + ci;
    sm_[nsub] = Smax[idx];
    si_[nsub] = Sinv[idx];
    const __bf16* qp = Qh + (size_t)(n0 + nsub * 16 + ci) * 64;
    qf[nsub][0] = *(const bf16x8*)(qp + g * 8);
    qf[nsub][1] = *(const bf16x8*)(qp + 32 + g * 8);
  }

  for (int rnd = 0; rnd < 16; ++rnd) {
    const int m0 = mstart + rnd * 32;
    // K A-frags (row=m=ci, k=d), shared by both n-subtiles
    bf16x8 ka[2], kb[2];
#pragma unroll
    for (int fm = 0; fm < 2; ++fm) {
      const __bf16* kp = Kh + (size_t)(m0 + fm * 16 + ci) * 64;
      ka[fm] = *(const bf16x8*)(kp + g * 8);
      kb[fm] = *(const bf16x8*)(kp + 32 + g * 8);
    }
    // ---- nsub 0: scores -> weights -> W2[0] ----
#pragma unroll
    for (int fm = 0; fm < 2; ++fm) {
      f32x4 s = (f32x4){0.f, 0.f, 0.f, 0.f};
      s = __builtin_amdgcn_mfma_f32_16x16x32_bf16(ka[fm], qf[0][0], s, 0, 0, 0);
      s = __builtin_amdgcn_mfma_f32_16x16x32_bf16(kb[fm], qf[0][1], s, 0, 0, 0);
#pragma unroll
      for (int r = 0; r < 4; ++r) {
        float wv = fexp2(s[r] - sm_[0]) * si_[0];
        int m = fm * 16 + g * 4 + r;
        W2[0][m * WSTRIDE + ci * 17 + h] = wv;
      }
    }
    __syncthreads();
    // ---- store W2[0] (rows n0..n0+15) overlapped with nsub 1 compute ----
    {
      size_t wbase = (((size_t)(b * 2048 + n0)) * 2048 + m0) * 16;
#pragma unroll
      for (int it = 0; it < 2; ++it) {
        int slot = threadIdx.x + it * 1024;       // slot = n*128 + m*4 + hq
        int n = slot >> 7, m = (slot >> 2) & 31, hq = slot & 3;
        const float* src = &W2[0][m * WSTRIDE + n * 17 + hq * 4];
        f32x4 v = {src[0], src[1], src[2], src[3]};
        __builtin_nontemporal_store(
            v, (f32x4*)(Wout + wbase + ((size_t)n * 2048 + m) * 16 + hq * 4));
      }
    }
#pragma unroll
    for (int fm = 0; fm < 2; ++fm) {
      f32x4 s = (f32x4){0.f, 0.f, 0.f, 0.f};
      s = __builtin_amdgcn_mfma_f32_16x16x32_bf16(ka[fm], qf[1][0], s, 0, 0, 0);
      s = __builtin_amdgcn_mfma_f32_16x16x32_bf16(kb[fm], qf[1][1], s, 0, 0, 0);
#pragma unroll
      for (int r = 0; r < 4; ++r) {
        float wv = fexp2(s[r] - sm_[1]) * si_[1];
        int m = fm * 16 + g * 4 + r;
        W2[1][m * WSTRIDE + ci * 17 + h] = wv;
      }
    }
    __syncthreads();
    // ---- store W2[1] (rows n0+16..n0+31) overlapped with next round ----
    {
      size_t wbase = (((size_t)(b * 2048 + n0 + 16)) * 2048 + m0) * 16;
#pragma unroll
      for (int it = 0; it < 2; ++it) {
        int slot = threadIdx.x + it * 1024;
        int n = slot >> 7, m = (slot >> 2) & 31, hq = slot & 3;
        const float* src = &W2[1][m * WSTRIDE + n * 17 + hq * 4];
        f32x4 v = {src[0], src[1], src[2], src[3]};
        __builtin_nontemporal_store(
            v, (f32x4*)(Wout + wbase + ((size_t)n * 2048 + m) * 16 + hq * 4));
      }
    }
  }
}

extern "C" void kernel_launch(void* const* d_in, const int* in_sizes, int n_in,
                              void* d_out, int out_size, void* d_ws, size_t ws_size,
                              hipStream_t stream) {
  const float* queries = (const float*)d_in[0];
  const float* Wq  = (const float*)d_in[1];
  const float* bq  = (const float*)d_in[2];
  const float* Wkv = (const float*)d_in[3];
  const float* bkv = (const float*)d_in[4];
  const float* Wo  = (const float*)d_in[5];
  const float* bo  = (const float*)d_in[6];
  const int Bsz = in_sizes[0] / (2048 * 1024);
  const int M = Bsz * 2048;

  size_t bf16_elems = (size_t)M * 1024 * 5 + (size_t)3072 * 1024 + (size_t)1024 * 1024;
  size_t f32_elems  = (size_t)M * 16 * 2;
  size_t need = bf16_elems * 2 + f32_elems * 4;
  if (ws_size < need) return;

  __bf16* Xbf   = (__bf16*)d_ws;
  __bf16* WcatT = Xbf + (size_t)M * 1024;
  __bf16* WoT   = WcatT + (size_t)3072 * 1024;
  __bf16* Qb    = WoT + (size_t)1024 * 1024;
  __bf16* Kb    = Qb + (size_t)M * 1024;
  __bf16* Vb    = Kb + (size_t)M * 1024;     // Vt [b][h][d][s]
  __bf16* Ob    = Vb + (size_t)M * 1024;
  float*  Smax  = (float*)(Ob + (size_t)M * 1024);
  float*  Sinv  = Smax + (size_t)M * 16;

  float* outp = (float*)d_out;
  float* wout = outp + (size_t)M * 1024;

  cvt_f32_bf16<<<(M * 1024) / (256 * 8), 256, 0, stream>>>(queries, Xbf, M * 1024);
  transpose_bf16<<<dim3(16, 16), 256, 0, stream>>>(Wq, WcatT, 1024, 1024);
  transpose_bf16<<<dim3(32, 16), 256, 0, stream>>>(Wkv, WcatT + (size_t)1024 * 1024, 1024, 2048);
  transpose_bf16<<<dim3(16, 16), 256, 0, stream>>>(Wo, WoT, 1024, 1024);
  gemm128<0><<<dim3(M / 128, 3072 / 128), 256, 0, stream>>>(
      Xbf, WcatT, M, 3072, 1024, bq, bkv, nullptr, Qb, Kb, Vb);
  statspv_kernel<<<Bsz * 256, 512, 0, stream>>>(Qb, Kb, Vb, Smax, Sinv, Ob);
  attn_w7<<<Bsz * 256, 1024, 0, stream>>>(Qb, Kb, Smax, Sinv, wout);
  gemm128<1><<<dim3(M / 128, 1024 / 128), 256, 0, stream>>>(
      Ob, WoT, M, 1024, 1024, bo, nullptr, outp, nullptr, nullptr, nullptr);
}

// Round 14
// 320.117 us; speedup vs baseline: 1.1452x; 1.0174x over previous
//
#include <hip/hip_runtime.h>

typedef __bf16 bf16x8 __attribute__((ext_vector_type(8)));
typedef __bf16 bf16x4 __attribute__((ext_vector_type(4)));
typedef __bf16 bf16x2 __attribute__((ext_vector_type(2)));
typedef float f32x4 __attribute__((ext_vector_type(4)));
typedef unsigned int u32;

// Problem constants: B (runtime), S=2048, D=1024, H=16, hd=64
#define QSCALE 0.18033688011112042f  // hd^-0.5 * log2(e), folded into Q
#define WSTRIDE 273                  // W2 row stride (odd mod 32 -> 2-way banks, free)

__device__ __forceinline__ void gld_lds16(const void* gsrc, void* ldst) {
  __builtin_amdgcn_global_load_lds(
      (const __attribute__((address_space(1))) u32*)gsrc,
      (__attribute__((address_space(3))) u32*)ldst, 16, 0, 0);
}

__device__ __forceinline__ float fexp2(float x) {
#if __has_builtin(__builtin_amdgcn_exp2f)
  return __builtin_amdgcn_exp2f(x);
#else
  return exp2f(x);
#endif
}

__device__ __forceinline__ u32 pkbf(float a, float b) {
  bf16x2 t; t[0] = (__bf16)a; t[1] = (__bf16)b;
  return __builtin_bit_cast(u32, t);
}

// ---------------- fused preamble: fp32->bf16 cvt + 3 weight transposes ----------------
// Block ranges: [0, cvtBlocks) = cvt(queries->Xbf);
//   then 256 blocks Wq->WcatT, 512 blocks Wkv->WcatT+1M, 256 blocks Wo->WoT.
// Bodies byte-identical to the R13-validated cvt_f32_bf16 / transpose_bf16.
__global__ __launch_bounds__(256) void prep_kernel(
    const float* __restrict__ queries, const float* __restrict__ Wq,
    const float* __restrict__ Wkv, const float* __restrict__ Wo,
    __bf16* __restrict__ Xbf, __bf16* __restrict__ WcatT, __bf16* __restrict__ WoT,
    int M)
{
  const int cvtBlocks = (M * 1024) / 2048;
  int bb = blockIdx.x;
  if (bb < cvtBlocks) {
    int i = (bb * 256 + threadIdx.x) * 8;
    const float4* p = (const float4*)(queries + i);
    float4 a = p[0], b = p[1];
    bf16x8 v;
    v[0] = (__bf16)a.x; v[1] = (__bf16)a.y; v[2] = (__bf16)a.z; v[3] = (__bf16)a.w;
    v[4] = (__bf16)b.x; v[5] = (__bf16)b.y; v[6] = (__bf16)b.z; v[7] = (__bf16)b.w;
    *(bf16x8*)(Xbf + i) = v;
    return;
  }
  bb -= cvtBlocks;
  const float* src; __bf16* dst; int R, C, c0, r0;
  if (bb < 256) {
    src = Wq;  dst = WcatT; R = 1024; C = 1024;
    c0 = (bb & 15) * 64; r0 = (bb >> 4) * 64;
  } else if (bb < 768) {
    int b2 = bb - 256;
    src = Wkv; dst = WcatT + (size_t)1024 * 1024; R = 1024; C = 2048;
    c0 = (b2 & 31) * 64; r0 = (b2 >> 5) * 64;
  } else {
    int b2 = bb - 768;
    src = Wo;  dst = WoT; R = 1024; C = 1024;
    c0 = (b2 & 15) * 64; r0 = (b2 >> 4) * 64;
  }
  __shared__ float tile[64 * 65];
  int t = threadIdx.x;
  for (int i = 0; i < 16; ++i) {
    int idx = t + i * 256; int rr = idx >> 6, cc = idx & 63;
    tile[rr * 65 + cc] = src[(size_t)(r0 + rr) * C + (c0 + cc)];
  }
  __syncthreads();
  for (int i = 0; i < 16; ++i) {
    int idx = t + i * 256; int cc = idx >> 6, rr = idx & 63;
    dst[(size_t)(c0 + cc) * R + (r0 + rr)] = (__bf16)tile[rr * 65 + cc];
  }
}

// ---------------- 128x128-tile bf16 MFMA GEMM, A[M][K] @ Bt[N][K]^T ----------------
template<int EPI>
__global__ __launch_bounds__(256) void gemm128(
    const __bf16* __restrict__ A, const __bf16* __restrict__ Bt,
    int M, int N, int K,
    const float* __restrict__ bias0, const float* __restrict__ bias1,
    float* __restrict__ outf,
    __bf16* __restrict__ Qo, __bf16* __restrict__ Ko, __bf16* __restrict__ Vt)
{
  __shared__ __bf16 As[128 * 32];
  __shared__ __bf16 Bs[128 * 32];
  const int m0 = blockIdx.x * 128, n0 = blockIdx.y * 128;
  const int t = threadIdx.x, lane = t & 63, wave = t >> 6;
  const int wr = wave >> 1, wc = wave & 1;
  const int g = lane >> 4, ci = lane & 15;
  f32x4 acc[4][4];
#pragma unroll
  for (int i = 0; i < 4; ++i)
#pragma unroll
    for (int j = 0; j < 4; ++j) acc[i][j] = (f32x4){0.f, 0.f, 0.f, 0.f};

  const char* Ab = (const char*)A;
  const char* Bb = (const char*)Bt;
  for (int k0 = 0; k0 < K; k0 += 32) {
#pragma unroll
    for (int i = 0; i < 2; ++i) {
      int o = wave * 2048 + i * 1024 + lane * 16;
      int row = o >> 6, cb = o & 63;
      gld_lds16(Ab + ((size_t)(m0 + row) * K + k0) * 2 + cb, (char*)As + o);
      gld_lds16(Bb + ((size_t)(n0 + row) * K + k0) * 2 + cb, (char*)Bs + o);
    }
    __syncthreads();
    bf16x8 af[4], bfr[4];
#pragma unroll
    for (int i = 0; i < 4; ++i)
      af[i] = *(const bf16x8*)((const char*)As + (wr * 64 + i * 16 + ci) * 64 + g * 16);
#pragma unroll
    for (int j = 0; j < 4; ++j)
      bfr[j] = *(const bf16x8*)((const char*)Bs + (wc * 64 + j * 16 + ci) * 64 + g * 16);
#pragma unroll
    for (int i = 0; i < 4; ++i)
#pragma unroll
      for (int j = 0; j < 4; ++j)
        acc[i][j] = __builtin_amdgcn_mfma_f32_16x16x32_bf16(af[i], bfr[j], acc[i][j], 0, 0, 0);
    __syncthreads();
  }
#pragma unroll
  for (int j = 0; j < 4; ++j) {
    int c = n0 + wc * 64 + j * 16 + ci;
    float bias;
    if (EPI == 0) bias = (c < 1024) ? bias0[c] : bias1[c - 1024];
    else          bias = bias0[c];
#pragma unroll
    for (int i = 0; i < 4; ++i) {
      int rbase = m0 + wr * 64 + i * 16 + g * 4;
      if (EPI == 1) {
#pragma unroll
        for (int r = 0; r < 4; ++r)
          outf[(size_t)(rbase + r) * 1024 + c] = acc[i][j][r] + bias;
      } else {
        int b = rbase >> 11, n = rbase & 2047;
        if (c < 1024) {
          int h = c >> 6, d = c & 63;
#pragma unroll
          for (int r = 0; r < 4; ++r)
            Qo[(((size_t)(b * 16 + h)) * 2048 + n + r) * 64 + d] =
                (__bf16)((acc[i][j][r] + bias) * QSCALE);
        } else if (c < 2048) {
          int c2 = c - 1024; int h = c2 >> 6, d = c2 & 63;
#pragma unroll
          for (int r = 0; r < 4; ++r)
            Ko[(((size_t)(b * 16 + h)) * 2048 + n + r) * 64 + d] =
                (__bf16)(acc[i][j][r] + bias);
        } else {
          int c2 = c - 2048; int h = c2 >> 6, d = c2 & 63;
          bf16x4 pk;
#pragma unroll
          for (int r = 0; r < 4; ++r) pk[r] = (__bf16)(acc[i][j][r] + bias);
          *(bf16x4*)(Vt + ((size_t)(b * 16 + h) * 64 + d) * 2048 + n) = pk;
        }
      }
    }
  }
}

// ---------------- statspv: softmax stats + flash PV (O single-writer) ----------------
// [validated R13: 512-thr blocks, 2 blocks/CU, K double-buffered, one barrier/round;
//  stats row mapping via shuffles (R8)]
__global__ __launch_bounds__(512, 4) void statspv_kernel(
    const __bf16* __restrict__ Q, const __bf16* __restrict__ K, const __bf16* __restrict__ Vt,
    float* __restrict__ Smax, float* __restrict__ Sinv, __bf16* __restrict__ Ob)
{
  __shared__ __bf16 Kl[2][128 * 64]; // [m128][d64], chunk c stored at c^(m&7); dbuf
  __shared__ __bf16 Pp[8][16][40];   // per-wave P patch: [wave][n16][40] (80B rows)
  const int blk = blockIdx.x;
  const int b = blk >> 8, rem = blk & 255;
  const int h = rem >> 4, nsx = rem & 15;
  const int w = threadIdx.x >> 6, lane = threadIdx.x & 63;
  const int g = lane >> 4, ci = lane & 15;
  const size_t bh = (size_t)(b * 16 + h);
  const __bf16* Qh = Q + bh * 2048 * 64;
  const __bf16* Kh = K + bh * 2048 * 64;
  const __bf16* Vh = Vt + bh * 64 * 2048;   // [d][s]
  const int n0 = nsx * 128 + w * 16;

  bf16x8 qf0 = *(const bf16x8*)(Qh + (size_t)(n0 + ci) * 64 + g * 8);
  bf16x8 qf1 = *(const bf16x8*)(Qh + (size_t)(n0 + ci) * 64 + 32 + g * 8);

  // stage decode: 512 threads x 16B x 2 issues = 16KB tile
  const int so0 = threadIdx.x * 16;
  const int so1 = so0 + 512 * 16;
  const int sm0 = so0 >> 7, sc0 = ((so0 >> 4) & 7) ^ (sm0 & 7);
  const int sm1 = so1 >> 7, sc1 = ((so1 >> 4) & 7) ^ (sm1 & 7);

  float rm = -3.0e30f, rs = 0.f;
  f32x4 oacc[4];
#pragma unroll
  for (int fd = 0; fd < 4; ++fd) oacc[fd] = (f32x4){0.f, 0.f, 0.f, 0.f};

  // prologue: stage tile 0
  gld_lds16(Kh + ((size_t)sm0) * 64 + sc0 * 8, (char*)Kl[0] + so0);
  gld_lds16(Kh + ((size_t)sm1) * 64 + sc1 * 8, (char*)Kl[0] + so1);
  __syncthreads();
  int cur = 0;

  for (int mt = 0; mt < 2048; mt += 128) {
    // issue next tile's stage FIRST (hides under this tile's compute)
    if (mt + 128 < 2048) {
      gld_lds16(Kh + ((size_t)(mt + 128 + sm0)) * 64 + sc0 * 8, (char*)Kl[cur ^ 1] + so0);
      gld_lds16(Kh + ((size_t)(mt + 128 + sm1)) * 64 + sc1 * 8, (char*)Kl[cur ^ 1] + so1);
    }
    const char* Kc = (const char*)Kl[cur];
    f32x4 st[8];
#pragma unroll
    for (int fm = 0; fm < 8; ++fm) {
      int row = fm * 16 + ci;
      bf16x8 ka = *(const bf16x8*)(Kc + row * 128 + ((g ^ (ci & 7)) * 16));
      bf16x8 kb = *(const bf16x8*)(Kc + row * 128 + (((4 + g) ^ (ci & 7)) * 16));
      st[fm] = (f32x4){0.f, 0.f, 0.f, 0.f};
      st[fm] = __builtin_amdgcn_mfma_f32_16x16x32_bf16(ka, qf0, st[fm], 0, 0, 0);
      st[fm] = __builtin_amdgcn_mfma_f32_16x16x32_bf16(kb, qf1, st[fm], 0, 0, 0);
    }
    // per-round row max for col n=ci (cross-g combine so all 4 g-lanes agree)
    float tm = -3.0e30f;
#pragma unroll
    for (int fm = 0; fm < 8; ++fm)
#pragma unroll
      for (int r = 0; r < 4; ++r) tm = fmaxf(tm, st[fm][r]);
    tm = fmaxf(tm, __shfl_xor(tm, 16, 64));
    tm = fmaxf(tm, __shfl_xor(tm, 32, 64));
    float nm = fmaxf(rm, tm);
    float scale = fexp2(rm - nm);       // scale for row n = ci
    rs *= scale;
    // oacc rows are n = g*4+r -> fetch those rows' scales from lanes g*4+r
    f32x4 rsc;
#pragma unroll
    for (int r = 0; r < 4; ++r) rsc[r] = __shfl(scale, g * 4 + r, 64);
#pragma unroll
    for (int fd = 0; fd < 4; ++fd)
#pragma unroll
      for (int r = 0; r < 4; ++r) oacc[fd][r] *= rsc[r];
    rm = nm;
    // PV + sum, one 32-m slice at a time (P bf16 patch, validated layout)
    float ts = 0.f;
#pragma unroll
    for (int kk2 = 0; kk2 < 4; ++kk2) {
#pragma unroll
      for (int fm2 = 0; fm2 < 2; ++fm2) {
        f32x4 s = st[kk2 * 2 + fm2];
        f32x4 wv;
#pragma unroll
        for (int r = 0; r < 4; ++r) { wv[r] = fexp2(s[r] - nm); ts += wv[r]; }
        u32* pb = (u32*)((char*)&Pp[w][ci][0] + (fm2 * 8 + g * 2) * 4);
        pb[0] = pkbf(wv[0], wv[1]);
        pb[1] = pkbf(wv[2], wv[3]);
      }
      bf16x8 pa = *(const bf16x8*)((const char*)&Pp[w][ci][0] + g * 16);
#pragma unroll
      for (int fd = 0; fd < 4; ++fd) {
        bf16x8 vf = *(const bf16x8*)(Vh + (size_t)(fd * 16 + ci) * 2048 +
                                     mt + kk2 * 32 + g * 8);
        oacc[fd] = __builtin_amdgcn_mfma_f32_16x16x32_bf16(pa, vf, oacc[fd], 0, 0, 0);
      }
    }
    rs += ts;
    __syncthreads();
    cur ^= 1;
  }
  // combine per-lane partial sums across the 4 g-groups (rm already common)
#pragma unroll
  for (int off = 16; off <= 32; off <<= 1) {
    float om = __shfl_xor(rm, off, 64);
    float os = __shfl_xor(rs, off, 64);
    float nm = fmaxf(rm, om);
    rs = rs * fexp2(rm - nm) + os * fexp2(om - nm);
    rm = nm;
  }
  const float inv = 1.0f / rs;          // for row n = ci
  if (lane < 16) {
    size_t idx = bh * 2048 + n0 + ci;
    Smax[idx] = rm;
    Sinv[idx] = inv;
  }
  // O write rows are n = g*4+r -> fetch those rows' inv from lanes g*4+r
  f32x4 rinv;
#pragma unroll
  for (int r = 0; r < 4; ++r) rinv[r] = __shfl(inv, g * 4 + r, 64);
#pragma unroll
  for (int fd = 0; fd < 4; ++fd)
#pragma unroll
    for (int r = 0; r < 4; ++r) {
      int n = n0 + g * 4 + r;
      Ob[((size_t)(b * 2048 + n)) * 1024 + h * 64 + fd * 16 + ci] =
          (__bf16)(oacc[fd][r] * rinv[r]);
    }
}

// ---------------- weights-only kernel (v12 = R9 structure + odd W2 stride) ----------------
// [validated R12] Block = (b, n-tile 32, m-quarter 512); 16 waves = 16 heads;
// grid = B*256; 2 blocks/CU.
__global__ __launch_bounds__(1024, 8) void attn_w7(
    const __bf16* __restrict__ Q, const __bf16* __restrict__ K,
    const float* __restrict__ Smax, const float* __restrict__ Sinv,
    float* __restrict__ Wout)
{
  __shared__ float W2[2][32 * WSTRIDE];   // 2 x 34.9 KB (nsub ping-pong)
  // bijective XCD swizzle: each XCD gets a contiguous 64-block chunk = one (b, mq)
  const int nwg = gridDim.x, cpx = nwg >> 3;
  const int o = blockIdx.x;
  const int blk = (o & 7) * cpx + (o >> 3);
  const int b = blk >> 8, r = blk & 255;
  const int mq = r >> 6, nt = r & 63;
  const int n0 = nt * 32, mstart = mq * 512;
  const int h = threadIdx.x >> 6;            // wave = head
  const int lane = threadIdx.x & 63;
  const int g = lane >> 4, ci = lane & 15;
  const size_t bh = (size_t)(b * 16 + h);
  const __bf16* Qh = Q + bh * 2048 * 64;
  const __bf16* Kh = K + bh * 2048 * 64;

  float sm_[2], si_[2];
  bf16x8 qf[2][2];
#pragma unroll
  for (int nsub = 0; nsub < 2; ++nsub) {
    size_t idx = bh * 2048 + n0 + nsub * 16 + ci;
    sm_[nsub] = Smax[idx];
    si_[nsub] = Sinv[idx];
    const __bf16* qp = Qh + (size_t)(n0 + nsub * 16 + ci) * 64;
    qf[nsub][0] = *(const bf16x8*)(qp + g * 8);
    qf[nsub][1] = *(const bf16x8*)(qp + 32 + g * 8);
  }

  for (int rnd = 0; rnd < 16; ++rnd) {
    const int m0 = mstart + rnd * 32;
    // K A-frags (row=m=ci, k=d), shared by both n-subtiles
    bf16x8 ka[2], kb[2];
#pragma unroll
    for (int fm = 0; fm < 2; ++fm) {
      const __bf16* kp = Kh + (size_t)(m0 + fm * 16 + ci) * 64;
      ka[fm] = *(const bf16x8*)(kp + g * 8);
      kb[fm] = *(const bf16x8*)(kp + 32 + g * 8);
    }
    // ---- nsub 0: scores -> weights -> W2[0] ----
#pragma unroll
    for (int fm = 0; fm < 2; ++fm) {
      f32x4 s = (f32x4){0.f, 0.f, 0.f, 0.f};
      s = __builtin_amdgcn_mfma_f32_16x16x32_bf16(ka[fm], qf[0][0], s, 0, 0, 0);
      s = __builtin_amdgcn_mfma_f32_16x16x32_bf16(kb[fm], qf[0][1], s, 0, 0, 0);
#pragma unroll
      for (int r = 0; r < 4; ++r) {
        float wv = fexp2(s[r] - sm_[0]) * si_[0];
        int m = fm * 16 + g * 4 + r;
        W2[0][m * WSTRIDE + ci * 17 + h] = wv;
      }
    }
    __syncthreads();
    // ---- store W2[0] (rows n0..n0+15) overlapped with nsub 1 compute ----
    {
      size_t wbase = (((size_t)(b * 2048 + n0)) * 2048 + m0) * 16;
#pragma unroll
      for (int it = 0; it < 2; ++it) {
        int slot = threadIdx.x + it * 1024;       // slot = n*128 + m*4 + hq
        int n = slot >> 7, m = (slot >> 2) & 31, hq = slot & 3;
        const float* src = &W2[0][m * WSTRIDE + n * 17 + hq * 4];
        f32x4 v = {src[0], src[1], src[2], src[3]};
        __builtin_nontemporal_store(
            v, (f32x4*)(Wout + wbase + ((size_t)n * 2048 + m) * 16 + hq * 4));
      }
    }
#pragma unroll
    for (int fm = 0; fm < 2; ++fm) {
      f32x4 s = (f32x4){0.f, 0.f, 0.f, 0.f};
      s = __builtin_amdgcn_mfma_f32_16x16x32_bf16(ka[fm], qf[1][0], s, 0, 0, 0);
      s = __builtin_amdgcn_mfma_f32_16x16x32_bf16(kb[fm], qf[1][1], s, 0, 0, 0);
#pragma unroll
      for (int r = 0; r < 4; ++r) {
        float wv = fexp2(s[r] - sm_[1]) * si_[1];
        int m = fm * 16 + g * 4 + r;
        W2[1][m * WSTRIDE + ci * 17 + h] = wv;
      }
    }
    __syncthreads();
    // ---- store W2[1] (rows n0+16..n0+31) overlapped with next round ----
    {
      size_t wbase = (((size_t)(b * 2048 + n0 + 16)) * 2048 + m0) * 16;
#pragma unroll
      for (int it = 0; it < 2; ++it) {
        int slot = threadIdx.x + it * 1024;
        int n = slot >> 7, m = (slot >> 2) & 31, hq = slot & 3;
        const float* src = &W2[1][m * WSTRIDE + n * 17 + hq * 4];
        f32x4 v = {src[0], src[1], src[2], src[3]};
        __builtin_nontemporal_store(
            v, (f32x4*)(Wout + wbase + ((size_t)n * 2048 + m) * 16 + hq * 4));
      }
    }
  }
}

extern "C" void kernel_launch(void* const* d_in, const int* in_sizes, int n_in,
                              void* d_out, int out_size, void* d_ws, size_t ws_size,
                              hipStream_t stream) {
  const float* queries = (const float*)d_in[0];
  const float* Wq  = (const float*)d_in[1];
  const float* bq  = (const float*)d_in[2];
  const float* Wkv = (const float*)d_in[3];
  const float* bkv = (const float*)d_in[4];
  const float* Wo  = (const float*)d_in[5];
  const float* bo  = (const float*)d_in[6];
  const int Bsz = in_sizes[0] / (2048 * 1024);
  const int M = Bsz * 2048;

  size_t bf16_elems = (size_t)M * 1024 * 5 + (size_t)3072 * 1024 + (size_t)1024 * 1024;
  size_t f32_elems  = (size_t)M * 16 * 2;
  size_t need = bf16_elems * 2 + f32_elems * 4;
  if (ws_size < need) return;

  __bf16* Xbf   = (__bf16*)d_ws;
  __bf16* WcatT = Xbf + (size_t)M * 1024;
  __bf16* WoT   = WcatT + (size_t)3072 * 1024;
  __bf16* Qb    = WoT + (size_t)1024 * 1024;
  __bf16* Kb    = Qb + (size_t)M * 1024;
  __bf16* Vb    = Kb + (size_t)M * 1024;     // Vt [b][h][d][s]
  __bf16* Ob    = Vb + (size_t)M * 1024;
  float*  Smax  = (float*)(Ob + (size_t)M * 1024);
  float*  Sinv  = Smax + (size_t)M * 16;

  float* outp = (float*)d_out;
  float* wout = outp + (size_t)M * 1024;

  const int cvtBlocks = (M * 1024) / 2048;
  prep_kernel<<<cvtBlocks + 1024, 256, 0, stream>>>(
      queries, Wq, Wkv, Wo, Xbf, WcatT, WoT, M);
  gemm128<0><<<dim3(M / 128, 3072 / 128), 256, 0, stream>>>(
      Xbf, WcatT, M, 3072, 1024, bq, bkv, nullptr, Qb, Kb, Vb);
  statspv_kernel<<<Bsz * 256, 512, 0, stream>>>(Qb, Kb, Vb, Smax, Sinv, Ob);
  attn_w7<<<Bsz * 256, 1024, 0, stream>>>(Qb, Kb, Smax, Sinv, wout);
  gemm128<1><<<dim3(M / 128, 1024 / 128), 256, 0, stream>>>(
      Ob, WoT, M, 1024, 1024, bo, nullptr, outp, nullptr, nullptr, nullptr);
}

// Round 15
// 308.661 us; speedup vs baseline: 1.1877x; 1.0371x over previous
//
#include <hip/hip_runtime.h>

typedef __bf16 bf16x8 __attribute__((ext_vector_type(8)));
typedef __bf16 bf16x4 __attribute__((ext_vector_type(4)));
typedef __bf16 bf16x2 __attribute__((ext_vector_type(2)));
typedef float f32x4 __attribute__((ext_vector_type(4)));
typedef unsigned int u32;

// Problem constants: B (runtime), S=2048, D=1024, H=16, hd=64
#define QSCALE 0.18033688011112042f  // hd^-0.5 * log2(e), folded into Q
#define WSTRIDE 273                  // W2 row stride (odd mod 32 -> 2-way banks, free)

__device__ __forceinline__ void gld_lds16(const void* gsrc, void* ldst) {
  __builtin_amdgcn_global_load_lds(
      (const __attribute__((address_space(1))) u32*)gsrc,
      (__attribute__((address_space(3))) u32*)ldst, 16, 0, 0);
}

__device__ __forceinline__ float fexp2(float x) {
#if __has_builtin(__builtin_amdgcn_exp2f)
  return __builtin_amdgcn_exp2f(x);
#else
  return exp2f(x);
#endif
}

__device__ __forceinline__ u32 pkbf(float a, float b) {
  bf16x2 t; t[0] = (__bf16)a; t[1] = (__bf16)b;
  return __builtin_bit_cast(u32, t);
}

// ---------------- fused preamble: fp32->bf16 cvt + 3 weight transposes ----------------
// [validated R14]
__global__ __launch_bounds__(256) void prep_kernel(
    const float* __restrict__ queries, const float* __restrict__ Wq,
    const float* __restrict__ Wkv, const float* __restrict__ Wo,
    __bf16* __restrict__ Xbf, __bf16* __restrict__ WcatT, __bf16* __restrict__ WoT,
    int M)
{
  const int cvtBlocks = (M * 1024) / 2048;
  int bb = blockIdx.x;
  if (bb < cvtBlocks) {
    int i = (bb * 256 + threadIdx.x) * 8;
    const float4* p = (const float4*)(queries + i);
    float4 a = p[0], b = p[1];
    bf16x8 v;
    v[0] = (__bf16)a.x; v[1] = (__bf16)a.y; v[2] = (__bf16)a.z; v[3] = (__bf16)a.w;
    v[4] = (__bf16)b.x; v[5] = (__bf16)b.y; v[6] = (__bf16)b.z; v[7] = (__bf16)b.w;
    *(bf16x8*)(Xbf + i) = v;
    return;
  }
  bb -= cvtBlocks;
  const float* src; __bf16* dst; int R, C, c0, r0;
  if (bb < 256) {
    src = Wq;  dst = WcatT; R = 1024; C = 1024;
    c0 = (bb & 15) * 64; r0 = (bb >> 4) * 64;
  } else if (bb < 768) {
    int b2 = bb - 256;
    src = Wkv; dst = WcatT + (size_t)1024 * 1024; R = 1024; C = 2048;
    c0 = (b2 & 31) * 64; r0 = (b2 >> 5) * 64;
  } else {
    int b2 = bb - 768;
    src = Wo;  dst = WoT; R = 1024; C = 1024;
    c0 = (b2 & 15) * 64; r0 = (b2 >> 4) * 64;
  }
  __shared__ float tile[64 * 65];
  int t = threadIdx.x;
  for (int i = 0; i < 16; ++i) {
    int idx = t + i * 256; int rr = idx >> 6, cc = idx & 63;
    tile[rr * 65 + cc] = src[(size_t)(r0 + rr) * C + (c0 + cc)];
  }
  __syncthreads();
  for (int i = 0; i < 16; ++i) {
    int idx = t + i * 256; int cc = idx >> 6, rr = idx & 63;
    dst[(size_t)(c0 + cc) * R + (r0 + rr)] = (__bf16)tile[rr * 65 + cc];
  }
}

// ---------------- 128x128-tile bf16 MFMA GEMM, A[M][K] @ Bt[N][K]^T ----------------
// v15: BK 32 -> 64. Barrier count halves (2 per 64-K). LDS tiles are [128][64]
// with statspv's VALIDATED both-sides XOR pattern: stage source chunk
// sc = ((o>>4)&7) ^ (row&7) into linear LDS dest (rule #21: gld_lds writes
// linearly, so the GLOBAL source is pre-swizzled); frag read chunk
// (kk*4+g) ^ (ci&7) (involution; row&7==ci&7 since row offsets are x16).
// Read conflicts 8-way -> 2-way. MFMA k-slices: chunk kk*4+g = elements
// kk*32 + g*8, identical to the validated BK=32 frag layout per subtile.
// Epilogue byte-identical to R14.
template<int EPI>
__global__ __launch_bounds__(256) void gemm128(
    const __bf16* __restrict__ A, const __bf16* __restrict__ Bt,
    int M, int N, int K,
    const float* __restrict__ bias0, const float* __restrict__ bias1,
    float* __restrict__ outf,
    __bf16* __restrict__ Qo, __bf16* __restrict__ Ko, __bf16* __restrict__ Vt)
{
  __shared__ __bf16 As[128 * 64];
  __shared__ __bf16 Bs[128 * 64];
  const int m0 = blockIdx.x * 128, n0 = blockIdx.y * 128;
  const int t = threadIdx.x, lane = t & 63, wave = t >> 6;
  const int wr = wave >> 1, wc = wave & 1;
  const int g = lane >> 4, ci = lane & 15;
  f32x4 acc[4][4];
#pragma unroll
  for (int i = 0; i < 4; ++i)
#pragma unroll
    for (int j = 0; j < 4; ++j) acc[i][j] = (f32x4){0.f, 0.f, 0.f, 0.f};

  const char* Ab = (const char*)A;
  const char* Bb = (const char*)Bt;
  for (int k0 = 0; k0 < K; k0 += 64) {
#pragma unroll
    for (int i = 0; i < 4; ++i) {
      int o = i * 4096 + t * 16;
      int row = o >> 7;                       // 128 B per (row, 64 k-elems)
      int sc = ((o >> 4) & 7) ^ (row & 7);    // pre-swizzled global chunk
      gld_lds16(Ab + ((size_t)(m0 + row) * K + k0) * 2 + sc * 16, (char*)As + o);
      gld_lds16(Bb + ((size_t)(n0 + row) * K + k0) * 2 + sc * 16, (char*)Bs + o);
    }
    __syncthreads();
#pragma unroll
    for (int kk = 0; kk < 2; ++kk) {
      bf16x8 af[4], bfr[4];
#pragma unroll
      for (int i = 0; i < 4; ++i) {
        int r = wr * 64 + i * 16 + ci;
        af[i] = *(const bf16x8*)((const char*)As + r * 128 +
                                 (((kk * 4 + g) ^ (ci & 7)) * 16));
      }
#pragma unroll
      for (int j = 0; j < 4; ++j) {
        int r = wc * 64 + j * 16 + ci;
        bfr[j] = *(const bf16x8*)((const char*)Bs + r * 128 +
                                  (((kk * 4 + g) ^ (ci & 7)) * 16));
      }
#pragma unroll
      for (int i = 0; i < 4; ++i)
#pragma unroll
        for (int j = 0; j < 4; ++j)
          acc[i][j] = __builtin_amdgcn_mfma_f32_16x16x32_bf16(af[i], bfr[j], acc[i][j], 0, 0, 0);
    }
    __syncthreads();
  }
#pragma unroll
  for (int j = 0; j < 4; ++j) {
    int c = n0 + wc * 64 + j * 16 + ci;
    float bias;
    if (EPI == 0) bias = (c < 1024) ? bias0[c] : bias1[c - 1024];
    else          bias = bias0[c];
#pragma unroll
    for (int i = 0; i < 4; ++i) {
      int rbase = m0 + wr * 64 + i * 16 + g * 4;
      if (EPI == 1) {
#pragma unroll
        for (int r = 0; r < 4; ++r)
          outf[(size_t)(rbase + r) * 1024 + c] = acc[i][j][r] + bias;
      } else {
        int b = rbase >> 11, n = rbase & 2047;
        if (c < 1024) {
          int h = c >> 6, d = c & 63;
#pragma unroll
          for (int r = 0; r < 4; ++r)
            Qo[(((size_t)(b * 16 + h)) * 2048 + n + r) * 64 + d] =
                (__bf16)((acc[i][j][r] + bias) * QSCALE);
        } else if (c < 2048) {
          int c2 = c - 1024; int h = c2 >> 6, d = c2 & 63;
#pragma unroll
          for (int r = 0; r < 4; ++r)
            Ko[(((size_t)(b * 16 + h)) * 2048 + n + r) * 64 + d] =
                (__bf16)(acc[i][j][r] + bias);
        } else {
          int c2 = c - 2048; int h = c2 >> 6, d = c2 & 63;
          bf16x4 pk;
#pragma unroll
          for (int r = 0; r < 4; ++r) pk[r] = (__bf16)(acc[i][j][r] + bias);
          *(bf16x4*)(Vt + ((size_t)(b * 16 + h) * 64 + d) * 2048 + n) = pk;
        }
      }
    }
  }
}

// ---------------- statspv: softmax stats + flash PV (O single-writer) ----------------
// [validated R13: 512-thr blocks, 2 blocks/CU, K double-buffered, one barrier/round;
//  stats row mapping via shuffles (R8)]
__global__ __launch_bounds__(512, 4) void statspv_kernel(
    const __bf16* __restrict__ Q, const __bf16* __restrict__ K, const __bf16* __restrict__ Vt,
    float* __restrict__ Smax, float* __restrict__ Sinv, __bf16* __restrict__ Ob)
{
  __shared__ __bf16 Kl[2][128 * 64]; // [m128][d64], chunk c stored at c^(m&7); dbuf
  __shared__ __bf16 Pp[8][16][40];   // per-wave P patch: [wave][n16][40] (80B rows)
  const int blk = blockIdx.x;
  const int b = blk >> 8, rem = blk & 255;
  const int h = rem >> 4, nsx = rem & 15;
  const int w = threadIdx.x >> 6, lane = threadIdx.x & 63;
  const int g = lane >> 4, ci = lane & 15;
  const size_t bh = (size_t)(b * 16 + h);
  const __bf16* Qh = Q + bh * 2048 * 64;
  const __bf16* Kh = K + bh * 2048 * 64;
  const __bf16* Vh = Vt + bh * 64 * 2048;   // [d][s]
  const int n0 = nsx * 128 + w * 16;

  bf16x8 qf0 = *(const bf16x8*)(Qh + (size_t)(n0 + ci) * 64 + g * 8);
  bf16x8 qf1 = *(const bf16x8*)(Qh + (size_t)(n0 + ci) * 64 + 32 + g * 8);

  // stage decode: 512 threads x 16B x 2 issues = 16KB tile
  const int so0 = threadIdx.x * 16;
  const int so1 = so0 + 512 * 16;
  const int sm0 = so0 >> 7, sc0 = ((so0 >> 4) & 7) ^ (sm0 & 7);
  const int sm1 = so1 >> 7, sc1 = ((so1 >> 4) & 7) ^ (sm1 & 7);

  float rm = -3.0e30f, rs = 0.f;
  f32x4 oacc[4];
#pragma unroll
  for (int fd = 0; fd < 4; ++fd) oacc[fd] = (f32x4){0.f, 0.f, 0.f, 0.f};

  // prologue: stage tile 0
  gld_lds16(Kh + ((size_t)sm0) * 64 + sc0 * 8, (char*)Kl[0] + so0);
  gld_lds16(Kh + ((size_t)sm1) * 64 + sc1 * 8, (char*)Kl[0] + so1);
  __syncthreads();
  int cur = 0;

  for (int mt = 0; mt < 2048; mt += 128) {
    // issue next tile's stage FIRST (hides under this tile's compute)
    if (mt + 128 < 2048) {
      gld_lds16(Kh + ((size_t)(mt + 128 + sm0)) * 64 + sc0 * 8, (char*)Kl[cur ^ 1] + so0);
      gld_lds16(Kh + ((size_t)(mt + 128 + sm1)) * 64 + sc1 * 8, (char*)Kl[cur ^ 1] + so1);
    }
    const char* Kc = (const char*)Kl[cur];
    f32x4 st[8];
#pragma unroll
    for (int fm = 0; fm < 8; ++fm) {
      int row = fm * 16 + ci;
      bf16x8 ka = *(const bf16x8*)(Kc + row * 128 + ((g ^ (ci & 7)) * 16));
      bf16x8 kb = *(const bf16x8*)(Kc + row * 128 + (((4 + g) ^ (ci & 7)) * 16));
      st[fm] = (f32x4){0.f, 0.f, 0.f, 0.f};
      st[fm] = __builtin_amdgcn_mfma_f32_16x16x32_bf16(ka, qf0, st[fm], 0, 0, 0);
      st[fm] = __builtin_amdgcn_mfma_f32_16x16x32_bf16(kb, qf1, st[fm], 0, 0, 0);
    }
    // per-round row max for col n=ci (cross-g combine so all 4 g-lanes agree)
    float tm = -3.0e30f;
#pragma unroll
    for (int fm = 0; fm < 8; ++fm)
#pragma unroll
      for (int r = 0; r < 4; ++r) tm = fmaxf(tm, st[fm][r]);
    tm = fmaxf(tm, __shfl_xor(tm, 16, 64));
    tm = fmaxf(tm, __shfl_xor(tm, 32, 64));
    float nm = fmaxf(rm, tm);
    float scale = fexp2(rm - nm);       // scale for row n = ci
    rs *= scale;
    // oacc rows are n = g*4+r -> fetch those rows' scales from lanes g*4+r
    f32x4 rsc;
#pragma unroll
    for (int r = 0; r < 4; ++r) rsc[r] = __shfl(scale, g * 4 + r, 64);
#pragma unroll
    for (int fd = 0; fd < 4; ++fd)
#pragma unroll
      for (int r = 0; r < 4; ++r) oacc[fd][r] *= rsc[r];
    rm = nm;
    // PV + sum, one 32-m slice at a time (P bf16 patch, validated layout)
    float ts = 0.f;
#pragma unroll
    for (int kk2 = 0; kk2 < 4; ++kk2) {
#pragma unroll
      for (int fm2 = 0; fm2 < 2; ++fm2) {
        f32x4 s = st[kk2 * 2 + fm2];
        f32x4 wv;
#pragma unroll
        for (int r = 0; r < 4; ++r) { wv[r] = fexp2(s[r] - nm); ts += wv[r]; }
        u32* pb = (u32*)((char*)&Pp[w][ci][0] + (fm2 * 8 + g * 2) * 4);
        pb[0] = pkbf(wv[0], wv[1]);
        pb[1] = pkbf(wv[2], wv[3]);
      }
      bf16x8 pa = *(const bf16x8*)((const char*)&Pp[w][ci][0] + g * 16);
#pragma unroll
      for (int fd = 0; fd < 4; ++fd) {
        bf16x8 vf = *(const bf16x8*)(Vh + (size_t)(fd * 16 + ci) * 2048 +
                                     mt + kk2 * 32 + g * 8);
        oacc[fd] = __builtin_amdgcn_mfma_f32_16x16x32_bf16(pa, vf, oacc[fd], 0, 0, 0);
      }
    }
    rs += ts;
    __syncthreads();
    cur ^= 1;
  }
  // combine per-lane partial sums across the 4 g-groups (rm already common)
#pragma unroll
  for (int off = 16; off <= 32; off <<= 1) {
    float om = __shfl_xor(rm, off, 64);
    float os = __shfl_xor(rs, off, 64);
    float nm = fmaxf(rm, om);
    rs = rs * fexp2(rm - nm) + os * fexp2(om - nm);
    rm = nm;
  }
  const float inv = 1.0f / rs;          // for row n = ci
  if (lane < 16) {
    size_t idx = bh * 2048 + n0 + ci;
    Smax[idx] = rm;
    Sinv[idx] = inv;
  }
  // O write rows are n = g*4+r -> fetch those rows' inv from lanes g*4+r
  f32x4 rinv;
#pragma unroll
  for (int r = 0; r < 4; ++r) rinv[r] = __shfl(inv, g * 4 + r, 64);
#pragma unroll
  for (int fd = 0; fd < 4; ++fd)
#pragma unroll
    for (int r = 0; r < 4; ++r) {
      int n = n0 + g * 4 + r;
      Ob[((size_t)(b * 2048 + n)) * 1024 + h * 64 + fd * 16 + ci] =
          (__bf16)(oacc[fd][r] * rinv[r]);
    }
}

// ---------------- weights-only kernel (v12 = R9 structure + odd W2 stride) ----------------
// [validated R12] Block = (b, n-tile 32, m-quarter 512); 16 waves = 16 heads;
// grid = B*256; 2 blocks/CU.
__global__ __launch_bounds__(1024, 8) void attn_w7(
    const __bf16* __restrict__ Q, const __bf16* __restrict__ K,
    const float* __restrict__ Smax, const float* __restrict__ Sinv,
    float* __restrict__ Wout)
{
  __shared__ float W2[2][32 * WSTRIDE];   // 2 x 34.9 KB (nsub ping-pong)
  // bijective XCD swizzle: each XCD gets a contiguous 64-block chunk = one (b, mq)
  const int nwg = gridDim.x, cpx = nwg >> 3;
  const int o = blockIdx.x;
  const int blk = (o & 7) * cpx + (o >> 3);
  const int b = blk >> 8, r = blk & 255;
  const int mq = r >> 6, nt = r & 63;
  const int n0 = nt * 32, mstart = mq * 512;
  const int h = threadIdx.x >> 6;            // wave = head
  const int lane = threadIdx.x & 63;
  const int g = lane >> 4, ci = lane & 15;
  const size_t bh = (size_t)(b * 16 + h);
  const __bf16* Qh = Q + bh * 2048 * 64;
  const __bf16* Kh = K + bh * 2048 * 64;

  float sm_[2], si_[2];
  bf16x8 qf[2][2];
#pragma unroll
  for (int nsub = 0; nsub < 2; ++nsub) {
    size_t idx = bh * 2048 + n0 + nsub * 16 + ci;
    sm_[nsub] = Smax[idx];
    si_[nsub] = Sinv[idx];
    const __bf16* qp = Qh + (size_t)(n0 + nsub * 16 + ci) * 64;
    qf[nsub][0] = *(const bf16x8*)(qp + g * 8);
    qf[nsub][1] = *(const bf16x8*)(qp + 32 + g * 8);
  }

  for (int rnd = 0; rnd < 16; ++rnd) {
    const int m0 = mstart + rnd * 32;
    // K A-frags (row=m=ci, k=d), shared by both n-subtiles
    bf16x8 ka[2], kb[2];
#pragma unroll
    for (int fm = 0; fm < 2; ++fm) {
      const __bf16* kp = Kh + (size_t)(m0 + fm * 16 + ci) * 64;
      ka[fm] = *(const bf16x8*)(kp + g * 8);
      kb[fm] = *(const bf16x8*)(kp + 32 + g * 8);
    }
    // ---- nsub 0: scores -> weights -> W2[0] ----
#pragma unroll
    for (int fm = 0; fm < 2; ++fm) {
      f32x4 s = (f32x4){0.f, 0.f, 0.f, 0.f};
      s = __builtin_amdgcn_mfma_f32_16x16x32_bf16(ka[fm], qf[0][0], s, 0, 0, 0);
      s = __builtin_amdgcn_mfma_f32_16x16x32_bf16(kb[fm], qf[0][1], s, 0, 0, 0);
#pragma unroll
      for (int r = 0; r < 4; ++r) {
        float wv = fexp2(s[r] - sm_[0]) * si_[0];
        int m = fm * 16 + g * 4 + r;
        W2[0][m * WSTRIDE + ci * 17 + h] = wv;
      }
    }
    __syncthreads();
    // ---- store W2[0] (rows n0..n0+15) overlapped with nsub 1 compute ----
    {
      size_t wbase = (((size_t)(b * 2048 + n0)) * 2048 + m0) * 16;
#pragma unroll
      for (int it = 0; it < 2; ++it) {
        int slot = threadIdx.x + it * 1024;       // slot = n*128 + m*4 + hq
        int n = slot >> 7, m = (slot >> 2) & 31, hq = slot & 3;
        const float* src = &W2[0][m * WSTRIDE + n * 17 + hq * 4];
        f32x4 v = {src[0], src[1], src[2], src[3]};
        __builtin_nontemporal_store(
            v, (f32x4*)(Wout + wbase + ((size_t)n * 2048 + m) * 16 + hq * 4));
      }
    }
#pragma unroll
    for (int fm = 0; fm < 2; ++fm) {
      f32x4 s = (f32x4){0.f, 0.f, 0.f, 0.f};
      s = __builtin_amdgcn_mfma_f32_16x16x32_bf16(ka[fm], qf[1][0], s, 0, 0, 0);
      s = __builtin_amdgcn_mfma_f32_16x16x32_bf16(kb[fm], qf[1][1], s, 0, 0, 0);
#pragma unroll
      for (int r = 0; r < 4; ++r) {
        float wv = fexp2(s[r] - sm_[1]) * si_[1];
        int m = fm * 16 + g * 4 + r;
        W2[1][m * WSTRIDE + ci * 17 + h] = wv;
      }
    }
    __syncthreads();
    // ---- store W2[1] (rows n0+16..n0+31) overlapped with next round ----
    {
      size_t wbase = (((size_t)(b * 2048 + n0 + 16)) * 2048 + m0) * 16;
#pragma unroll
      for (int it = 0; it < 2; ++it) {
        int slot = threadIdx.x + it * 1024;
        int n = slot >> 7, m = (slot >> 2) & 31, hq = slot & 3;
        const float* src = &W2[1][m * WSTRIDE + n * 17 + hq * 4];
        f32x4 v = {src[0], src[1], src[2], src[3]};
        __builtin_nontemporal_store(
            v, (f32x4*)(Wout + wbase + ((size_t)n * 2048 + m) * 16 + hq * 4));
      }
    }
  }
}

extern "C" void kernel_launch(void* const* d_in, const int* in_sizes, int n_in,
                              void* d_out, int out_size, void* d_ws, size_t ws_size,
                              hipStream_t stream) {
  const float* queries = (const float*)d_in[0];
  const float* Wq  = (const float*)d_in[1];
  const float* bq  = (const float*)d_in[2];
  const float* Wkv = (const float*)d_in[3];
  const float* bkv = (const float*)d_in[4];
  const float* Wo  = (const float*)d_in[5];
  const float* bo  = (const float*)d_in[6];
  const int Bsz = in_sizes[0] / (2048 * 1024);
  const int M = Bsz * 2048;

  size_t bf16_elems = (size_t)M * 1024 * 5 + (size_t)3072 * 1024 + (size_t)1024 * 1024;
  size_t f32_elems  = (size_t)M * 16 * 2;
  size_t need = bf16_elems * 2 + f32_elems * 4;
  if (ws_size < need) return;

  __bf16* Xbf   = (__bf16*)d_ws;
  __bf16* WcatT = Xbf + (size_t)M * 1024;
  __bf16* WoT   = WcatT + (size_t)3072 * 1024;
  __bf16* Qb    = WoT + (size_t)1024 * 1024;
  __bf16* Kb    = Qb + (size_t)M * 1024;
  __bf16* Vb    = Kb + (size_t)M * 1024;     // Vt [b][h][d][s]
  __bf16* Ob    = Vb + (size_t)M * 1024;
  float*  Smax  = (float*)(Ob + (size_t)M * 1024);
  float*  Sinv  = Smax + (size_t)M * 16;

  float* outp = (float*)d_out;
  float* wout = outp + (size_t)M * 1024;

  const int cvtBlocks = (M * 1024) / 2048;
  prep_kernel<<<cvtBlocks + 1024, 256, 0, stream>>>(
      queries, Wq, Wkv, Wo, Xbf, WcatT, WoT, M);
  gemm128<0><<<dim3(M / 128, 3072 / 128), 256, 0, stream>>>(
      Xbf, WcatT, M, 3072, 1024, bq, bkv, nullptr, Qb, Kb, Vb);
  statspv_kernel<<<Bsz * 256, 512, 0, stream>>>(Qb, Kb, Vb, Smax, Sinv, Ob);
  attn_w7<<<Bsz * 256, 1024, 0, stream>>>(Qb, Kb, Smax, Sinv, wout);
  gemm128<1><<<dim3(M / 128, 1024 / 128), 256, 0, stream>>>(
      Ob, WoT, M, 1024, 1024, bo, nullptr, outp, nullptr, nullptr, nullptr);
}

// Round 16
// 240.218 us; speedup vs baseline: 1.5261x; 1.2849x over previous
//
#include <hip/hip_runtime.h>

typedef __bf16 bf16x8 __attribute__((ext_vector_type(8)));
typedef __bf16 bf16x4 __attribute__((ext_vector_type(4)));
typedef __bf16 bf16x2 __attribute__((ext_vector_type(2)));
typedef float f32x4 __attribute__((ext_vector_type(4)));
typedef unsigned int u32;

// Problem constants: B (runtime), S=2048, D=1024, H=16, hd=64
#define QSCALE 0.18033688011112042f  // hd^-0.5 * log2(e), folded into Q
#define WSTRIDE 273                  // W2 row stride (odd mod 32 -> 2-way banks, free)

__device__ __forceinline__ void gld_lds16(const void* gsrc, void* ldst) {
  __builtin_amdgcn_global_load_lds(
      (const __attribute__((address_space(1))) u32*)gsrc,
      (__attribute__((address_space(3))) u32*)ldst, 16, 0, 0);
}

__device__ __forceinline__ float fexp2(float x) {
#if __has_builtin(__builtin_amdgcn_exp2f)
  return __builtin_amdgcn_exp2f(x);
#else
  return exp2f(x);
#endif
}

__device__ __forceinline__ u32 pkbf(float a, float b) {
  bf16x2 t; t[0] = (__bf16)a; t[1] = (__bf16)b;
  return __builtin_bit_cast(u32, t);
}

// ---------------- fused preamble: fp32->bf16 cvt + 3 weight transposes ----------------
// [validated R14]
__global__ __launch_bounds__(256) void prep_kernel(
    const float* __restrict__ queries, const float* __restrict__ Wq,
    const float* __restrict__ Wkv, const float* __restrict__ Wo,
    __bf16* __restrict__ Xbf, __bf16* __restrict__ WcatT, __bf16* __restrict__ WoT,
    int M)
{
  const int cvtBlocks = (M * 1024) / 2048;
  int bb = blockIdx.x;
  if (bb < cvtBlocks) {
    int i = (bb * 256 + threadIdx.x) * 8;
    const float4* p = (const float4*)(queries + i);
    float4 a = p[0], b = p[1];
    bf16x8 v;
    v[0] = (__bf16)a.x; v[1] = (__bf16)a.y; v[2] = (__bf16)a.z; v[3] = (__bf16)a.w;
    v[4] = (__bf16)b.x; v[5] = (__bf16)b.y; v[6] = (__bf16)b.z; v[7] = (__bf16)b.w;
    *(bf16x8*)(Xbf + i) = v;
    return;
  }
  bb -= cvtBlocks;
  const float* src; __bf16* dst; int R, C, c0, r0;
  if (bb < 256) {
    src = Wq;  dst = WcatT; R = 1024; C = 1024;
    c0 = (bb & 15) * 64; r0 = (bb >> 4) * 64;
  } else if (bb < 768) {
    int b2 = bb - 256;
    src = Wkv; dst = WcatT + (size_t)1024 * 1024; R = 1024; C = 2048;
    c0 = (b2 & 31) * 64; r0 = (b2 >> 5) * 64;
  } else {
    int b2 = bb - 768;
    src = Wo;  dst = WoT; R = 1024; C = 1024;
    c0 = (b2 & 15) * 64; r0 = (b2 >> 4) * 64;
  }
  __shared__ float tile[64 * 65];
  int t = threadIdx.x;
  for (int i = 0; i < 16; ++i) {
    int idx = t + i * 256; int rr = idx >> 6, cc = idx & 63;
    tile[rr * 65 + cc] = src[(size_t)(r0 + rr) * C + (c0 + cc)];
  }
  __syncthreads();
  for (int i = 0; i < 16; ++i) {
    int idx = t + i * 256; int cc = idx >> 6, rr = idx & 63;
    dst[(size_t)(c0 + cc) * R + (r0 + rr)] = (__bf16)tile[rr * 65 + cc];
  }
}

// ---------------- 128x128-tile bf16 MFMA GEMM, A[M][K] @ Bt[N][K]^T ----------------
// [validated R15: BK=64, both-sides XOR swizzle, 2 barriers per 64-K]
template<int EPI>
__global__ __launch_bounds__(256) void gemm128(
    const __bf16* __restrict__ A, const __bf16* __restrict__ Bt,
    int M, int N, int K,
    const float* __restrict__ bias0, const float* __restrict__ bias1,
    float* __restrict__ outf,
    __bf16* __restrict__ Qo, __bf16* __restrict__ Ko, __bf16* __restrict__ Vt)
{
  __shared__ __bf16 As[128 * 64];
  __shared__ __bf16 Bs[128 * 64];
  const int m0 = blockIdx.x * 128, n0 = blockIdx.y * 128;
  const int t = threadIdx.x, lane = t & 63, wave = t >> 6;
  const int wr = wave >> 1, wc = wave & 1;
  const int g = lane >> 4, ci = lane & 15;
  f32x4 acc[4][4];
#pragma unroll
  for (int i = 0; i < 4; ++i)
#pragma unroll
    for (int j = 0; j < 4; ++j) acc[i][j] = (f32x4){0.f, 0.f, 0.f, 0.f};

  const char* Ab = (const char*)A;
  const char* Bb = (const char*)Bt;
  for (int k0 = 0; k0 < K; k0 += 64) {
#pragma unroll
    for (int i = 0; i < 4; ++i) {
      int o = i * 4096 + t * 16;
      int row = o >> 7;
      int sc = ((o >> 4) & 7) ^ (row & 7);
      gld_lds16(Ab + ((size_t)(m0 + row) * K + k0) * 2 + sc * 16, (char*)As + o);
      gld_lds16(Bb + ((size_t)(n0 + row) * K + k0) * 2 + sc * 16, (char*)Bs + o);
    }
    __syncthreads();
#pragma unroll
    for (int kk = 0; kk < 2; ++kk) {
      bf16x8 af[4], bfr[4];
#pragma unroll
      for (int i = 0; i < 4; ++i) {
        int r = wr * 64 + i * 16 + ci;
        af[i] = *(const bf16x8*)((const char*)As + r * 128 +
                                 (((kk * 4 + g) ^ (ci & 7)) * 16));
      }
#pragma unroll
      for (int j = 0; j < 4; ++j) {
        int r = wc * 64 + j * 16 + ci;
        bfr[j] = *(const bf16x8*)((const char*)Bs + r * 128 +
                                  (((kk * 4 + g) ^ (ci & 7)) * 16));
      }
#pragma unroll
      for (int i = 0; i < 4; ++i)
#pragma unroll
        for (int j = 0; j < 4; ++j)
          acc[i][j] = __builtin_amdgcn_mfma_f32_16x16x32_bf16(af[i], bfr[j], acc[i][j], 0, 0, 0);
    }
    __syncthreads();
  }
#pragma unroll
  for (int j = 0; j < 4; ++j) {
    int c = n0 + wc * 64 + j * 16 + ci;
    float bias;
    if (EPI == 0) bias = (c < 1024) ? bias0[c] : bias1[c - 1024];
    else          bias = bias0[c];
#pragma unroll
    for (int i = 0; i < 4; ++i) {
      int rbase = m0 + wr * 64 + i * 16 + g * 4;
      if (EPI == 1) {
#pragma unroll
        for (int r = 0; r < 4; ++r)
          outf[(size_t)(rbase + r) * 1024 + c] = acc[i][j][r] + bias;
      } else {
        int b = rbase >> 11, n = rbase & 2047;
        if (c < 1024) {
          int h = c >> 6, d = c & 63;
#pragma unroll
          for (int r = 0; r < 4; ++r)
            Qo[(((size_t)(b * 16 + h)) * 2048 + n + r) * 64 + d] =
                (__bf16)((acc[i][j][r] + bias) * QSCALE);
        } else if (c < 2048) {
          int c2 = c - 1024; int h = c2 >> 6, d = c2 & 63;
#pragma unroll
          for (int r = 0; r < 4; ++r)
            Ko[(((size_t)(b * 16 + h)) * 2048 + n + r) * 64 + d] =
                (__bf16)(acc[i][j][r] + bias);
        } else {
          int c2 = c - 2048; int h = c2 >> 6, d = c2 & 63;
          bf16x4 pk;
#pragma unroll
          for (int r = 0; r < 4; ++r) pk[r] = (__bf16)(acc[i][j][r] + bias);
          *(bf16x4*)(Vt + ((size_t)(b * 16 + h) * 64 + d) * 2048 + n) = pk;
        }
      }
    }
  }
}

// ---------------- statspv: softmax stats + flash PV (O single-writer) ----------------
// [R13 validated structure] + v16: V staged in LDS (double-buffered, shared by all
// 8 waves) — kills the 8x redundant per-wave V port traffic. V stage follows the
// validated K-stage pattern extended to 16 chunks: pre-swizzled global source
// chunk c ^ (d&15), linear LDS dest (rule #21); PV read chunk (kk2*4+g) ^ ci
// (d&15 == ci for d = fd*16+ci) -> 2-way banks. Mapping verified vs the old
// direct load: row d = fd*16+ci, byte-in-row (kk2*32+g*8)*2 = (kk2*4+g)*16.
__global__ __launch_bounds__(512, 4) void statspv_kernel(
    const __bf16* __restrict__ Q, const __bf16* __restrict__ K, const __bf16* __restrict__ Vt,
    float* __restrict__ Smax, float* __restrict__ Sinv, __bf16* __restrict__ Ob)
{
  __shared__ __bf16 Kl[2][128 * 64]; // [m128][d64] rows 128B, chunk c at c^(m&7); dbuf
  __shared__ __bf16 Vl[2][64 * 128]; // [d64][m128] rows 256B, chunk c at c^(d&15); dbuf
  __shared__ __bf16 Pp[8][16][40];   // per-wave P patch: [wave][n16][40] (80B rows)
  const int blk = blockIdx.x;
  const int b = blk >> 8, rem = blk & 255;
  const int h = rem >> 4, nsx = rem & 15;
  const int w = threadIdx.x >> 6, lane = threadIdx.x & 63;
  const int g = lane >> 4, ci = lane & 15;
  const size_t bh = (size_t)(b * 16 + h);
  const __bf16* Qh = Q + bh * 2048 * 64;
  const __bf16* Kh = K + bh * 2048 * 64;
  const __bf16* Vh = Vt + bh * 64 * 2048;   // [d][s]
  const int n0 = nsx * 128 + w * 16;

  bf16x8 qf0 = *(const bf16x8*)(Qh + (size_t)(n0 + ci) * 64 + g * 8);
  bf16x8 qf1 = *(const bf16x8*)(Qh + (size_t)(n0 + ci) * 64 + 32 + g * 8);

  // K stage decode: 512 threads x 16B x 2 issues = 16KB tile
  const int so0 = threadIdx.x * 16;
  const int so1 = so0 + 512 * 16;
  const int sm0 = so0 >> 7, sc0 = ((so0 >> 4) & 7) ^ (sm0 & 7);
  const int sm1 = so1 >> 7, sc1 = ((so1 >> 4) & 7) ^ (sm1 & 7);
  // V stage decode: rows 256B (d), 16 chunks of 16B; chunk pre-swizzled by d&15
  const int vd0 = so0 >> 8, vc0 = ((so0 >> 4) & 15) ^ (vd0 & 15);
  const int vd1 = so1 >> 8, vc1 = ((so1 >> 4) & 15) ^ (vd1 & 15);

  float rm = -3.0e30f, rs = 0.f;
  f32x4 oacc[4];
#pragma unroll
  for (int fd = 0; fd < 4; ++fd) oacc[fd] = (f32x4){0.f, 0.f, 0.f, 0.f};

  // prologue: stage K+V tile 0
  gld_lds16(Kh + ((size_t)sm0) * 64 + sc0 * 8, (char*)Kl[0] + so0);
  gld_lds16(Kh + ((size_t)sm1) * 64 + sc1 * 8, (char*)Kl[0] + so1);
  gld_lds16(Vh + ((size_t)vd0) * 2048 + vc0 * 8, (char*)Vl[0] + so0);
  gld_lds16(Vh + ((size_t)vd1) * 2048 + vc1 * 8, (char*)Vl[0] + so1);
  __syncthreads();
  int cur = 0;

  for (int mt = 0; mt < 2048; mt += 128) {
    // issue next tile's stage FIRST (hides under this tile's compute)
    if (mt + 128 < 2048) {
      gld_lds16(Kh + ((size_t)(mt + 128 + sm0)) * 64 + sc0 * 8, (char*)Kl[cur ^ 1] + so0);
      gld_lds16(Kh + ((size_t)(mt + 128 + sm1)) * 64 + sc1 * 8, (char*)Kl[cur ^ 1] + so1);
      gld_lds16(Vh + ((size_t)vd0) * 2048 + mt + 128 + vc0 * 8, (char*)Vl[cur ^ 1] + so0);
      gld_lds16(Vh + ((size_t)vd1) * 2048 + mt + 128 + vc1 * 8, (char*)Vl[cur ^ 1] + so1);
    }
    const char* Kc = (const char*)Kl[cur];
    const char* Vc = (const char*)Vl[cur];
    f32x4 st[8];
#pragma unroll
    for (int fm = 0; fm < 8; ++fm) {
      int row = fm * 16 + ci;
      bf16x8 ka = *(const bf16x8*)(Kc + row * 128 + ((g ^ (ci & 7)) * 16));
      bf16x8 kb = *(const bf16x8*)(Kc + row * 128 + (((4 + g) ^ (ci & 7)) * 16));
      st[fm] = (f32x4){0.f, 0.f, 0.f, 0.f};
      st[fm] = __builtin_amdgcn_mfma_f32_16x16x32_bf16(ka, qf0, st[fm], 0, 0, 0);
      st[fm] = __builtin_amdgcn_mfma_f32_16x16x32_bf16(kb, qf1, st[fm], 0, 0, 0);
    }
    // per-round row max for col n=ci (cross-g combine so all 4 g-lanes agree)
    float tm = -3.0e30f;
#pragma unroll
    for (int fm = 0; fm < 8; ++fm)
#pragma unroll
      for (int r = 0; r < 4; ++r) tm = fmaxf(tm, st[fm][r]);
    tm = fmaxf(tm, __shfl_xor(tm, 16, 64));
    tm = fmaxf(tm, __shfl_xor(tm, 32, 64));
    float nm = fmaxf(rm, tm);
    float scale = fexp2(rm - nm);       // scale for row n = ci
    rs *= scale;
    // oacc rows are n = g*4+r -> fetch those rows' scales from lanes g*4+r
    f32x4 rsc;
#pragma unroll
    for (int r = 0; r < 4; ++r) rsc[r] = __shfl(scale, g * 4 + r, 64);
#pragma unroll
    for (int fd = 0; fd < 4; ++fd)
#pragma unroll
      for (int r = 0; r < 4; ++r) oacc[fd][r] *= rsc[r];
    rm = nm;
    // PV + sum, one 32-m slice at a time (P bf16 patch, validated layout)
    float ts = 0.f;
#pragma unroll
    for (int kk2 = 0; kk2 < 4; ++kk2) {
#pragma unroll
      for (int fm2 = 0; fm2 < 2; ++fm2) {
        f32x4 s = st[kk2 * 2 + fm2];
        f32x4 wv;
#pragma unroll
        for (int r = 0; r < 4; ++r) { wv[r] = fexp2(s[r] - nm); ts += wv[r]; }
        u32* pb = (u32*)((char*)&Pp[w][ci][0] + (fm2 * 8 + g * 2) * 4);
        pb[0] = pkbf(wv[0], wv[1]);
        pb[1] = pkbf(wv[2], wv[3]);
      }
      bf16x8 pa = *(const bf16x8*)((const char*)&Pp[w][ci][0] + g * 16);
#pragma unroll
      for (int fd = 0; fd < 4; ++fd) {
        int d = fd * 16 + ci;
        bf16x8 vf = *(const bf16x8*)(Vc + d * 256 + (((kk2 * 4 + g) ^ ci) * 16));
        oacc[fd] = __builtin_amdgcn_mfma_f32_16x16x32_bf16(pa, vf, oacc[fd], 0, 0, 0);
      }
    }
    rs += ts;
    __syncthreads();
    cur ^= 1;
  }
  // combine per-lane partial sums across the 4 g-groups (rm already common)
#pragma unroll
  for (int off = 16; off <= 32; off <<= 1) {
    float om = __shfl_xor(rm, off, 64);
    float os = __shfl_xor(rs, off, 64);
    float nm = fmaxf(rm, om);
    rs = rs * fexp2(rm - nm) + os * fexp2(om - nm);
    rm = nm;
  }
  const float inv = 1.0f / rs;          // for row n = ci
  if (lane < 16) {
    size_t idx = bh * 2048 + n0 + ci;
    Smax[idx] = rm;
    Sinv[idx] = inv;
  }
  // O write rows are n = g*4+r -> fetch those rows' inv from lanes g*4+r
  f32x4 rinv;
#pragma unroll
  for (int r = 0; r < 4; ++r) rinv[r] = __shfl(inv, g * 4 + r, 64);
#pragma unroll
  for (int fd = 0; fd < 4; ++fd)
#pragma unroll
    for (int r = 0; r < 4; ++r) {
      int n = n0 + g * 4 + r;
      Ob[((size_t)(b * 2048 + n)) * 1024 + h * 64 + fd * 16 + ci] =
          (__bf16)(oacc[fd][r] * rinv[r]);
    }
}

// ---------------- weights-only kernel (v12 = R9 structure + odd W2 stride) ----------------
// [validated R12] Block = (b, n-tile 32, m-quarter 512); 16 waves = 16 heads;
// grid = B*256; 2 blocks/CU.
__global__ __launch_bounds__(1024, 8) void attn_w7(
    const __bf16* __restrict__ Q, const __bf16* __restrict__ K,
    const float* __restrict__ Smax, const float* __restrict__ Sinv,
    float* __restrict__ Wout)
{
  __shared__ float W2[2][32 * WSTRIDE];   // 2 x 34.9 KB (nsub ping-pong)
  // bijective XCD swizzle: each XCD gets a contiguous 64-block chunk = one (b, mq)
  const int nwg = gridDim.x, cpx = nwg >> 3;
  const int o = blockIdx.x;
  const int blk = (o & 7) * cpx + (o >> 3);
  const int b = blk >> 8, r = blk & 255;
  const int mq = r >> 6, nt = r & 63;
  const int n0 = nt * 32, mstart = mq * 512;
  const int h = threadIdx.x >> 6;            // wave = head
  const int lane = threadIdx.x & 63;
  const int g = lane >> 4, ci = lane & 15;
  const size_t bh = (size_t)(b * 16 + h);
  const __bf16* Qh = Q + bh * 2048 * 64;
  const __bf16* Kh = K + bh * 2048 * 64;

  float sm_[2], si_[2];
  bf16x8 qf[2][2];
#pragma unroll
  for (int nsub = 0; nsub < 2; ++nsub) {
    size_t idx = bh * 2048 + n0 + nsub * 16 + ci;
    sm_[nsub] = Smax[idx];
    si_[nsub] = Sinv[idx];
    const __bf16* qp = Qh + (size_t)(n0 + nsub * 16 + ci) * 64;
    qf[nsub][0] = *(const bf16x8*)(qp + g * 8);
    qf[nsub][1] = *(const bf16x8*)(qp + 32 + g * 8);
  }

  for (int rnd = 0; rnd < 16; ++rnd) {
    const int m0 = mstart + rnd * 32;
    // K A-frags (row=m=ci, k=d), shared by both n-subtiles
    bf16x8 ka[2], kb[2];
#pragma unroll
    for (int fm = 0; fm < 2; ++fm) {
      const __bf16* kp = Kh + (size_t)(m0 + fm * 16 + ci) * 64;
      ka[fm] = *(const bf16x8*)(kp + g * 8);
      kb[fm] = *(const bf16x8*)(kp + 32 + g * 8);
    }
    // ---- nsub 0: scores -> weights -> W2[0] ----
#pragma unroll
    for (int fm = 0; fm < 2; ++fm) {
      f32x4 s = (f32x4){0.f, 0.f, 0.f, 0.f};
      s = __builtin_amdgcn_mfma_f32_16x16x32_bf16(ka[fm], qf[0][0], s, 0, 0, 0);
      s = __builtin_amdgcn_mfma_f32_16x16x32_bf16(kb[fm], qf[0][1], s, 0, 0, 0);
#pragma unroll
      for (int r = 0; r < 4; ++r) {
        float wv = fexp2(s[r] - sm_[0]) * si_[0];
        int m = fm * 16 + g * 4 + r;
        W2[0][m * WSTRIDE + ci * 17 + h] = wv;
      }
    }
    __syncthreads();
    // ---- store W2[0] (rows n0..n0+15) overlapped with nsub 1 compute ----
    {
      size_t wbase = (((size_t)(b * 2048 + n0)) * 2048 + m0) * 16;
#pragma unroll
      for (int it = 0; it < 2; ++it) {
        int slot = threadIdx.x + it * 1024;       // slot = n*128 + m*4 + hq
        int n = slot >> 7, m = (slot >> 2) & 31, hq = slot & 3;
        const float* src = &W2[0][m * WSTRIDE + n * 17 + hq * 4];
        f32x4 v = {src[0], src[1], src[2], src[3]};
        __builtin_nontemporal_store(
            v, (f32x4*)(Wout + wbase + ((size_t)n * 2048 + m) * 16 + hq * 4));
      }
    }
#pragma unroll
    for (int fm = 0; fm < 2; ++fm) {
      f32x4 s = (f32x4){0.f, 0.f, 0.f, 0.f};
      s = __builtin_amdgcn_mfma_f32_16x16x32_bf16(ka[fm], qf[1][0], s, 0, 0, 0);
      s = __builtin_amdgcn_mfma_f32_16x16x32_bf16(kb[fm], qf[1][1], s, 0, 0, 0);
#pragma unroll
      for (int r = 0; r < 4; ++r) {
        float wv = fexp2(s[r] - sm_[1]) * si_[1];
        int m = fm * 16 + g * 4 + r;
        W2[1][m * WSTRIDE + ci * 17 + h] = wv;
      }
    }
    __syncthreads();
    // ---- store W2[1] (rows n0+16..n0+31) overlapped with next round ----
    {
      size_t wbase = (((size_t)(b * 2048 + n0 + 16)) * 2048 + m0) * 16;
#pragma unroll
      for (int it = 0; it < 2; ++it) {
        int slot = threadIdx.x + it * 1024;
        int n = slot >> 7, m = (slot >> 2) & 31, hq = slot & 3;
        const float* src = &W2[1][m * WSTRIDE + n * 17 + hq * 4];
        f32x4 v = {src[0], src[1], src[2], src[3]};
        __builtin_nontemporal_store(
            v, (f32x4*)(Wout + wbase + ((size_t)n * 2048 + m) * 16 + hq * 4));
      }
    }
  }
}

extern "C" void kernel_launch(void* const* d_in, const int* in_sizes, int n_in,
                              void* d_out, int out_size, void* d_ws, size_t ws_size,
                              hipStream_t stream) {
  const float* queries = (const float*)d_in[0];
  const float* Wq  = (const float*)d_in[1];
  const float* bq  = (const float*)d_in[2];
  const float* Wkv = (const float*)d_in[3];
  const float* bkv = (const float*)d_in[4];
  const float* Wo  = (const float*)d_in[5];
  const float* bo  = (const float*)d_in[6];
  const int Bsz = in_sizes[0] / (2048 * 1024);
  const int M = Bsz * 2048;

  size_t bf16_elems = (size_t)M * 1024 * 5 + (size_t)3072 * 1024 + (size_t)1024 * 1024;
  size_t f32_elems  = (size_t)M * 16 * 2;
  size_t need = bf16_elems * 2 + f32_elems * 4;
  if (ws_size < need) return;

  __bf16* Xbf   = (__bf16*)d_ws;
  __bf16* WcatT = Xbf + (size_t)M * 1024;
  __bf16* WoT   = WcatT + (size_t)3072 * 1024;
  __bf16* Qb    = WoT + (size_t)1024 * 1024;
  __bf16* Kb    = Qb + (size_t)M * 1024;
  __bf16* Vb    = Kb + (size_t)M * 1024;     // Vt [b][h][d][s]
  __bf16* Ob    = Vb + (size_t)M * 1024;
  float*  Smax  = (float*)(Ob + (size_t)M * 1024);
  float*  Sinv  = Smax + (size_t)M * 16;

  float* outp = (float*)d_out;
  float* wout = outp + (size_t)M * 1024;

  const int cvtBlocks = (M * 1024) / 2048;
  prep_kernel<<<cvtBlocks + 1024, 256, 0, stream>>>(
      queries, Wq, Wkv, Wo, Xbf, WcatT, WoT, M);
  gemm128<0><<<dim3(M / 128, 3072 / 128), 256, 0, stream>>>(
      Xbf, WcatT, M, 3072, 1024, bq, bkv, nullptr, Qb, Kb, Vb);
  statspv_kernel<<<Bsz * 256, 512, 0, stream>>>(Qb, Kb, Vb, Smax, Sinv, Ob);
  attn_w7<<<Bsz * 256, 1024, 0, stream>>>(Qb, Kb, Smax, Sinv, wout);
  gemm128<1><<<dim3(M / 128, 1024 / 128), 256, 0, stream>>>(
      Ob, WoT, M, 1024, 1024, bo, nullptr, outp, nullptr, nullptr, nullptr);
}